// Round 13
// baseline (895.979 us; speedup 1.0000x reference)
//
#include <hip/hip_runtime.h>
#include <math.h>

// ---------------------------------------------------------------------------
// GATPolicy: 3x GATConv (with self loops) + mean-pool + MLP head.
// CSR-by-dst via dst-range sharded count/scatter (XCD-local lines); the
// count->prefix step is a SINGLE chained-scan kernel (ticket + decoupled
// lookback, agent-scope atomics). h stored FP8 e4m3 head-interleaved
// (byte pair at node*128+2*ch = ch of head0, ch of head1); agg inner loop is
// branch-free: 3 readlane + add + ushort load + cvt_pk_f32_fp8 + 2 fma /edge.
// Inter-layer features bf16; K=128 transforms via mfma_f32_16x16x32_bf16.
// Final-layer features bf16; W-pack + pooled-zero fused into one kernel.
// ---------------------------------------------------------------------------

#define LRELU(x) ((x) > 0.f ? (x) : 0.2f * (x))

typedef short bf16x8 __attribute__((ext_vector_type(8)));
typedef float f32x4 __attribute__((ext_vector_type(4)));
typedef float f32x2 __attribute__((ext_vector_type(2)));

__device__ __forceinline__ float readlane_f(float v, int lane) {
    return __int_as_float(__builtin_amdgcn_readlane(__float_as_int(v), lane));
}
__device__ __forceinline__ unsigned readlane_u(unsigned v, int lane) {
    return (unsigned)__builtin_amdgcn_readlane((int)v, lane);
}
__device__ __forceinline__ unsigned short f2bf(float f) {
    unsigned int u = __float_as_uint(f);
    u = (u + 0x7fffu + ((u >> 16) & 1u)) >> 16;  // RNE
    return (unsigned short)u;
}
__device__ __forceinline__ float bf2f(unsigned short u) {
    return __uint_as_float((unsigned int)u << 16);
}
__device__ __forceinline__ unsigned char f2fp8(float f) {
    return (unsigned char)(__builtin_amdgcn_cvt_pk_fp8_f32(f, f, 0, false) & 0xff);
}
__device__ __forceinline__ f32x2 fp8pair(unsigned int u) {
    return __builtin_amdgcn_cvt_pk_f32_fp8(u, false);  // bytes 0,1
}

// ---------------- CSR build (dst-range sharded, ILP-batched) ----------------

__global__ __launch_bounds__(256) void count_kernel(
    const int* __restrict__ dst, int* __restrict__ cursor, int e, int T, int n) {
    int x = blockIdx.x & 7;
    int lo = (int)(((long long)x * n) >> 3);
    int hi = (int)(((long long)(x + 1) * n) >> 3);
    int i0 = (blockIdx.x >> 3) * 256 + threadIdx.x;
    int d[8];
#pragma unroll
    for (int j = 0; j < 8; j++) {
        int ij = i0 + j * T;
        int dd = (ij < e) ? dst[ij] : -1;
        d[j] = (dd >= lo && dd < hi) ? dd : -1;
    }
#pragma unroll
    for (int j = 0; j < 8; j++) {
        if (d[j] >= 0) atomicAdd(&cursor[d[j]], 1);
    }
}

// Single-pass chained scan: exclusive prefix of cursor[] -> row_ptr[] and
// cursor[] (write pointers). Ticket ordering makes the lookback spin safe:
// a block's predecessor took its ticket earlier, so it is already resident.
__global__ __launch_bounds__(256) void scan_fused_kernel(
    int* __restrict__ cursor, int* __restrict__ row_ptr,
    int* __restrict__ ticket, int* __restrict__ partials,
    int* __restrict__ flags, int n, int nb) {
    __shared__ int lds[256];
    __shared__ int sbid, sbase;
    if (threadIdx.x == 0) sbid = atomicAdd(ticket, 1);
    __syncthreads();
    const int bid = sbid;
    const int i = bid * 256 + threadIdx.x;

    int v = (i < n) ? cursor[i] : 0;
    lds[threadIdx.x] = v;
    __syncthreads();
    for (int off = 1; off < 256; off <<= 1) {
        int t = (threadIdx.x >= off) ? lds[threadIdx.x - off] : 0;
        __syncthreads();
        lds[threadIdx.x] += t;
        __syncthreads();
    }
    const int total = lds[255];

    if (threadIdx.x == 0) {
        int base = 0;
        if (bid > 0) {
            while (__hip_atomic_load(&flags[bid - 1], __ATOMIC_ACQUIRE,
                                     __HIP_MEMORY_SCOPE_AGENT) == 0) {
                __builtin_amdgcn_s_sleep(1);
            }
            base = __hip_atomic_load(&partials[bid - 1], __ATOMIC_RELAXED,
                                     __HIP_MEMORY_SCOPE_AGENT);
        }
        __hip_atomic_store(&partials[bid], base + total, __ATOMIC_RELAXED,
                           __HIP_MEMORY_SCOPE_AGENT);
        __hip_atomic_store(&flags[bid], 1, __ATOMIC_RELEASE,
                           __HIP_MEMORY_SCOPE_AGENT);
        sbase = base;
    }
    __syncthreads();
    const int base = sbase;
    if (i < n) {
        int val = base + lds[threadIdx.x] - v;
        row_ptr[i] = val;
        cursor[i] = val;
    }
    if (bid == nb - 1 && threadIdx.x == 255) row_ptr[n] = base + total;
}

__global__ __launch_bounds__(256) void scatter_kernel(
    const int* __restrict__ src, const int* __restrict__ dst,
    int* __restrict__ cursor, int* __restrict__ col, int e, int T, int n) {
    int x = blockIdx.x & 7;
    int lo = (int)(((long long)x * n) >> 3);
    int hi = (int)(((long long)(x + 1) * n) >> 3);
    int i0 = (blockIdx.x >> 3) * 256 + threadIdx.x;
    int s[8], d[8];
#pragma unroll
    for (int j = 0; j < 8; j++) {
        int ij = i0 + j * T;
        bool v = ij < e;
        int dd = v ? dst[ij] : -1;
        d[j] = (dd >= lo && dd < hi) ? dd : -1;
        s[j] = v ? src[ij] : 0;
    }
    int p[8];
#pragma unroll
    for (int j = 0; j < 8; j++) {
        p[j] = (d[j] >= 0) ? atomicAdd(&cursor[d[j]], 1) : 0;
    }
#pragma unroll
    for (int j = 0; j < 8; j++) {
        if (d[j] >= 0) col[p[j]] = s[j];
    }
}

// ---------------- fused W-pack (W1 + W2) + pooled/cnt zero -----------------
// Wf[((t*4+s)*64+lane)*8 + j] = bf16( W[(s*32+(lane>>4)*8+j)*OUT + t*16+(lane&15)] )

__global__ __launch_bounds__(256) void pack_all_kernel(
    const float* __restrict__ W1, const float* __restrict__ W2,
    unsigned short* __restrict__ Wf1, unsigned short* __restrict__ Wf2,
    float* __restrict__ pooled, int poolN) {
    const int n1 = 8 * 4 * 64;   // W1 fragment rows (OUT=128)
    const int n2 = 4 * 4 * 64;   // W2 fragment rows (OUT=64)
    int gid = blockIdx.x * 256 + threadIdx.x;
    if (gid < n1) {
        int idx = gid;
        int lane = idx & 63, ts = idx >> 6;
        int s = ts & 3, t = ts >> 2;
        int quad = lane >> 4, cn = lane & 15;
#pragma unroll
        for (int j = 0; j < 8; j++)
            Wf1[idx * 8 + j] = f2bf(W1[(s * 32 + quad * 8 + j) * 128 + t * 16 + cn]);
    } else if (gid < n1 + n2) {
        int idx = gid - n1;
        int lane = idx & 63, ts = idx >> 6;
        int s = ts & 3, t = ts >> 2;
        int quad = lane >> 4, cn = lane & 15;
#pragma unroll
        for (int j = 0; j < 8; j++)
            Wf2[idx * 8 + j] = f2bf(W2[(s * 32 + quad * 8 + j) * 64 + t * 16 + cn]);
    } else {
        int k = gid - n1 - n2;
        if (k < poolN) pooled[k] = 0.f;
    }
}

// fp8 h byte position for channel c: 2-head interleaved pairs, 1-head flat
template <int OUT, int HEADS>
__device__ __forceinline__ int hpos8(int c) {
    return (HEADS == 2) ? (2 * (c & 63) + (c >> 6)) : c;
}

// ---------------- layer-0 transform (K=8, VALU): h(fp8)=x@W, as/ad ---------

template <int K, int OUT, int HEADS>
__global__ __launch_bounds__(OUT) void transform_kernel(
    const float* __restrict__ x, const float* __restrict__ W,
    const float* __restrict__ a_src, const float* __restrict__ a_dst,
    unsigned char* __restrict__ h, float* __restrict__ as_o, float* __restrict__ ad_o,
    int n) {
    constexpr int NPB = 8;
    __shared__ float xs[NPB][K];
    const int tid = threadIdx.x;
    const int node0 = blockIdx.x * NPB;

    for (int idx = tid; idx < NPB * K; idx += OUT) {
        int ni = idx / K, k = idx - ni * K;
        int ng = node0 + ni;
        xs[ni][k] = (ng < n) ? x[(size_t)ng * K + k] : 0.f;
    }
    __syncthreads();

    float acc[NPB];
#pragma unroll
    for (int i = 0; i < NPB; i++) acc[i] = 0.f;
    for (int k = 0; k < K; k++) {
        float wk = W[k * OUT + tid];
#pragma unroll
        for (int i = 0; i < NPB; i++) acc[i] += xs[i][k] * wk;
    }

    const int lane = tid & 63;
    const int head = (HEADS == 2) ? (tid >> 6) : 0;
    const int pos = hpos8<OUT, HEADS>(tid);
    const float av = a_src[tid];
    const float dv = a_dst[tid];
#pragma unroll
    for (int i = 0; i < NPB; i++) {
        int ng = node0 + i;
        if (ng >= n) break;
        h[(size_t)ng * OUT + pos] = f2fp8(acc[i]);
        float ps = acc[i] * av, pd = acc[i] * dv;
        for (int off = 32; off; off >>= 1) {
            ps += __shfl_xor(ps, off, 64);
            pd += __shfl_xor(pd, off, 64);
        }
        if (lane == 0) {
            as_o[ng * HEADS + head] = ps;
            ad_o[ng * HEADS + head] = pd;
        }
    }
}

// ---------------- MFMA transform (K=128): h(fp8)=xb(bf16)@W, as/ad ---------

template <int OUT, int HEADS>
__global__ __launch_bounds__(256) void transform_mfma_kernel(
    const unsigned short* __restrict__ xb, const unsigned short* __restrict__ Wf,
    const float* __restrict__ a_src, const float* __restrict__ a_dst,
    unsigned char* __restrict__ h, float* __restrict__ as_o, float* __restrict__ ad_o,
    int n) {
    constexpr int T = OUT / 16, S = 4;  // K = 128
    const int w = threadIdx.x >> 6, lane = threadIdx.x & 63;
    const int node0 = (blockIdx.x * 4 + w) * 16;
    if (node0 >= n) return;
    const int quad = lane >> 4, col = lane & 15;

    const int arow = node0 + col;
    const bool aok = arow < n;
    bf16x8 a[S];
    const unsigned short* xrow = xb + (size_t)arow * 128 + quad * 8;
#pragma unroll
    for (int s = 0; s < S; s++) {
        bf16x8 z = {0, 0, 0, 0, 0, 0, 0, 0};
        a[s] = aok ? *(const bf16x8*)(xrow + s * 32) : z;
    }

    f32x4 acc[T];
#pragma unroll
    for (int t = 0; t < T; t++) acc[t] = (f32x4){0.f, 0.f, 0.f, 0.f};

#pragma unroll
    for (int s = 0; s < S; s++) {
#pragma unroll
        for (int t = 0; t < T; t++) {
            bf16x8 b = *(const bf16x8*)(Wf + ((size_t)(t * S + s) * 64 + lane) * 8);
            acc[t] = __builtin_amdgcn_mfma_f32_16x16x32_bf16(a[s], b, acc[t], 0, 0, 0);
        }
    }

#pragma unroll
    for (int t = 0; t < T; t++) {
        int pos = hpos8<OUT, HEADS>(t * 16 + col);
#pragma unroll
        for (int r = 0; r < 4; r++) {
            int m = node0 + quad * 4 + r;
            if (m < n) h[(size_t)m * OUT + pos] = f2fp8(acc[t][r]);
        }
    }

#pragma unroll
    for (int r = 0; r < 4; r++) {
        float s0 = 0.f, s1 = 0.f, d0 = 0.f, d1 = 0.f;
#pragma unroll
        for (int t = 0; t < T; t++) {
            float av = a_src[t * 16 + col];
            float dv = a_dst[t * 16 + col];
            float v = acc[t][r];
            if (HEADS == 2 && t >= T / 2) { s1 += v * av; d1 += v * dv; }
            else                          { s0 += v * av; d0 += v * dv; }
        }
        for (int off = 8; off; off >>= 1) {
            s0 += __shfl_xor(s0, off, 64);
            d0 += __shfl_xor(d0, off, 64);
            if (HEADS == 2) {
                s1 += __shfl_xor(s1, off, 64);
                d1 += __shfl_xor(d1, off, 64);
            }
        }
        int m = node0 + quad * 4 + r;
        if (m < n) {
            if (HEADS == 2) {
                if (col == 0)      { as_o[m * 2] = s0;     ad_o[m * 2] = d0; }
                else if (col == 1) { as_o[m * 2 + 1] = s1; ad_o[m * 2 + 1] = d1; }
            } else {
                if (col == 0) { as_o[m] = s0; ad_o[m] = d0; }
            }
        }
    }
}

// ---------------- GAT aggregation, 2 heads (fp8 h): one wave per node ------

template <int ACT>  // 1 = elu
__global__ __launch_bounds__(256) void agg2_kernel(
    const int* __restrict__ row_ptr, const int* __restrict__ col,
    const unsigned char* __restrict__ h, const float2* __restrict__ as2,
    const float2* __restrict__ ad2, const float* __restrict__ bias,
    unsigned short* __restrict__ out, int n) {
    const int node = blockIdx.x * 4 + (threadIdx.x >> 6);
    const int lane = threadIdx.x & 63;
    if (node >= n) return;

    const int beg = row_ptr[node], end = row_ptr[node + 1];
    const float2 adv = ad2[node];
    const unsigned char* __restrict__ hb = h + 2 * lane;

    // self-loop
    const float2 avs = as2[node];
    float w0s = __expf(LRELU(avs.x + adv.x));
    float w1s = __expf(LRELU(avs.y + adv.y));
    unsigned int us = *(const unsigned short*)(hb + ((size_t)node << 7));
    f32x2 hvs = fp8pair(us);
    float accL = w0s * hvs.x, accH = w1s * hvs.y;
    float den0 = w0s, den1 = w1s;

    for (int base = beg; base < end; base += 64) {
        int cnt = end - base;
        if (cnt > 64) cnt = 64;
        int s = 0;
        float w0 = 0.f, w1 = 0.f;
        if (lane < cnt) {
            s = col[base + lane];
            float2 av = as2[s];
            w0 = __expf(LRELU(av.x + adv.x));
            w1 = __expf(LRELU(av.y + adv.y));
        }
        float t0 = w0, t1 = w1;
        for (int off = 32; off; off >>= 1) {
            t0 += __shfl_xor(t0, off, 64);
            t1 += __shfl_xor(t1, off, 64);
        }
        den0 += t0;
        den1 += t1;

        unsigned soff = (unsigned)s << 7;  // row byte offset (128 B)
        for (int j = 0; j < cnt; j += 4) {  // j <= 60; pads carry w=0
            unsigned oA = readlane_u(soff, j);
            unsigned oB = readlane_u(soff, j + 1);
            unsigned oC = readlane_u(soff, j + 2);
            unsigned oD = readlane_u(soff, j + 3);
            float a0 = readlane_f(w0, j),     a1 = readlane_f(w1, j);
            float b0 = readlane_f(w0, j + 1), b1 = readlane_f(w1, j + 1);
            float c0 = readlane_f(w0, j + 2), c1 = readlane_f(w1, j + 2);
            float d0 = readlane_f(w0, j + 3), d1 = readlane_f(w1, j + 3);
            unsigned uA = *(const unsigned short*)(hb + oA);
            unsigned uB = *(const unsigned short*)(hb + oB);
            unsigned uC = *(const unsigned short*)(hb + oC);
            unsigned uD = *(const unsigned short*)(hb + oD);
            f32x2 hA = fp8pair(uA);
            f32x2 hB = fp8pair(uB);
            f32x2 hC = fp8pair(uC);
            f32x2 hD = fp8pair(uD);
            accL += a0 * hA.x; accH += a1 * hA.y;
            accL += b0 * hB.x; accH += b1 * hB.y;
            accL += c0 * hC.x; accH += c1 * hC.y;
            accL += d0 * hD.x; accH += d1 * hD.y;
        }
    }

    float oL = accL / (den0 + 1e-16f) + bias[lane];
    float oH = accH / (den1 + 1e-16f) + bias[64 + lane];
    if (ACT) {
        oL = oL > 0.f ? oL : expm1f(oL);
        oH = oH > 0.f ? oH : expm1f(oH);
    }
    out[(size_t)node * 128 + lane] = f2bf(oL);
    out[(size_t)node * 128 + 64 + lane] = f2bf(oH);
}

// ---------------- GAT aggregation, 1 head (fp8 h, layer 2) -----------------
// Output bf16 (feeds pool only).

__global__ __launch_bounds__(256) void agg1_kernel(
    const int* __restrict__ row_ptr, const int* __restrict__ col,
    const unsigned char* __restrict__ h, const float* __restrict__ as1,
    const float* __restrict__ ad1, const float* __restrict__ bias,
    unsigned short* __restrict__ out, int n) {
    const int node = blockIdx.x * 4 + (threadIdx.x >> 6);
    const int lane = threadIdx.x & 63;
    if (node >= n) return;

    const int beg = row_ptr[node], end = row_ptr[node + 1];
    const float adv = ad1[node];
    const unsigned char* __restrict__ hb = h + lane;

    float ws = __expf(LRELU(as1[node] + adv));
    float acc = ws * fp8pair((unsigned)hb[(size_t)node << 6]).x;
    float den = ws;

    for (int base = beg; base < end; base += 64) {
        int cnt = end - base;
        if (cnt > 64) cnt = 64;
        int s = 0;
        float w = 0.f;
        if (lane < cnt) {
            s = col[base + lane];
            w = __expf(LRELU(as1[s] + adv));
        }
        float t = w;
        for (int off = 32; off; off >>= 1) t += __shfl_xor(t, off, 64);
        den += t;

        unsigned soff = (unsigned)s << 6;  // row byte offset (64 B)
        for (int j = 0; j < cnt; j += 4) {
            unsigned oA = readlane_u(soff, j);
            unsigned oB = readlane_u(soff, j + 1);
            unsigned oC = readlane_u(soff, j + 2);
            unsigned oD = readlane_u(soff, j + 3);
            float wA = readlane_f(w, j);
            float wB = readlane_f(w, j + 1);
            float wC = readlane_f(w, j + 2);
            float wD = readlane_f(w, j + 3);
            float hA = fp8pair((unsigned)hb[oA]).x;
            float hB = fp8pair((unsigned)hb[oB]).x;
            float hC = fp8pair((unsigned)hb[oC]).x;
            float hD = fp8pair((unsigned)hb[oD]).x;
            acc += wA * hA;
            acc += wB * hB;
            acc += wC * hC;
            acc += wD * hD;
        }
    }

    out[(size_t)node * 64 + lane] = f2bf(acc / (den + 1e-16f) + bias[lane]);
}

// ---------------- mean pool over sorted batch (bf16 in) --------------------

__global__ __launch_bounds__(256) void pool_kernel(
    const unsigned short* __restrict__ x, const int* __restrict__ batch,
    float* __restrict__ pooled, float* __restrict__ cnt, int n) {
    const int NPW = 16;
    int wid = blockIdx.x * (blockDim.x >> 6) + (threadIdx.x >> 6);
    int lane = threadIdx.x & 63;
    int start = wid * NPW;
    if (start >= n) return;
    int end = min(start + NPW, n);
    float acc = 0.f, c = 0.f;
    int cur = -1;
    for (int i = start; i < end; i++) {
        int b = batch[i];
        if (b != cur) {
            if (cur >= 0) {
                atomicAdd(&pooled[cur * 64 + lane], acc);
                if (lane == 0) atomicAdd(&cnt[cur], c);
            }
            cur = b;
            acc = 0.f;
            c = 0.f;
        }
        acc += bf2f(x[(size_t)i * 64 + lane]);
        c += 1.f;
    }
    if (cur >= 0) {
        atomicAdd(&pooled[cur * 64 + lane], acc);
        if (lane == 0) atomicAdd(&cnt[cur], c);
    }
}

// ---------------- MLP head: one block per graph row ------------------------

__global__ __launch_bounds__(256) void mlp_kernel(
    const float* __restrict__ pooled, const float* __restrict__ cnt,
    const float* __restrict__ obs,
    const float* __restrict__ Ws1, const float* __restrict__ bs1,
    const float* __restrict__ ln_g, const float* __restrict__ ln_b,
    const float* __restrict__ Ws2, const float* __restrict__ bs2,
    const float* __restrict__ Wa, const float* __restrict__ ba,
    const float* __restrict__ Wc, const float* __restrict__ bc,
    float* __restrict__ out_logits, float* __restrict__ out_value) {
    int b = blockIdx.x;
    int t = threadIdx.x;
    __shared__ float comb[192];
    __shared__ float red[256];
    __shared__ float hs[256];

    if (t < 64) {
        float c = cnt[b];
        c = c > 1.f ? c : 1.f;
        comb[t] = pooled[b * 64 + t] / c;
    } else if (t < 192) {
        comb[t] = obs[b * 128 + (t - 64)];
    }
    __syncthreads();

    float acc = bs1[t];
    for (int k = 0; k < 192; k++) acc += comb[k] * Ws1[k * 256 + t];

    red[t] = acc;
    __syncthreads();
    for (int off = 128; off; off >>= 1) {
        if (t < off) red[t] += red[t + off];
        __syncthreads();
    }
    float mu = red[0] / 256.f;
    __syncthreads();
    float d = acc - mu;
    red[t] = d * d;
    __syncthreads();
    for (int off = 128; off; off >>= 1) {
        if (t < off) red[t] += red[t + off];
        __syncthreads();
    }
    float var = red[0] / 256.f;
    float hn = d * rsqrtf(var + 1e-5f) * ln_g[t] + ln_b[t];
    hn = hn > 0.f ? hn : 0.f;
    __syncthreads();
    hs[t] = hn;
    __syncthreads();

    float acc2 = bs2[t];
    for (int k = 0; k < 256; k++) acc2 += hs[k] * Ws2[k * 256 + t];
    acc2 = acc2 > 0.f ? acc2 : 0.f;
    __syncthreads();
    hs[t] = acc2;
    __syncthreads();

    if (t < 16) {
        float a = ba[t];
        for (int k = 0; k < 256; k++) a += hs[k] * Wa[k * 16 + t];
        out_logits[b * 16 + t] = a;
    } else if (t == 16) {
        float v = bc[0];
        for (int k = 0; k < 256; k++) v += hs[k] * Wc[k];
        out_value[b] = v;
    }
}

// ---------------------------------------------------------------------------

extern "C" void kernel_launch(void* const* d_in, const int* in_sizes, int n_in,
                              void* d_out, int out_size, void* d_ws, size_t ws_size,
                              hipStream_t stream) {
    const float* obs    = (const float*)d_in[0];
    const float* nf     = (const float*)d_in[1];
    const int*   ei     = (const int*)d_in[2];
    const int*   batch  = (const int*)d_in[3];
    const float* W0     = (const float*)d_in[4];
    const float* a_src0 = (const float*)d_in[5];
    const float* a_dst0 = (const float*)d_in[6];
    const float* b0     = (const float*)d_in[7];
    const float* W1     = (const float*)d_in[8];
    const float* a_src1 = (const float*)d_in[9];
    const float* a_dst1 = (const float*)d_in[10];
    const float* b1     = (const float*)d_in[11];
    const float* W2     = (const float*)d_in[12];
    const float* a_src2 = (const float*)d_in[13];
    const float* a_dst2 = (const float*)d_in[14];
    const float* b2     = (const float*)d_in[15];
    const float* Ws1    = (const float*)d_in[16];
    const float* bs1    = (const float*)d_in[17];
    const float* ln_g   = (const float*)d_in[18];
    const float* ln_b   = (const float*)d_in[19];
    const float* Ws2    = (const float*)d_in[20];
    const float* bs2    = (const float*)d_in[21];
    const float* Wa     = (const float*)d_in[22];
    const float* ba     = (const float*)d_in[23];
    const float* Wc     = (const float*)d_in[24];
    const float* bc     = (const float*)d_in[25];

    const int N = in_sizes[3];
    const int E = in_sizes[2] / 2;
    const int B = in_sizes[0] / 128;
    const int* src = ei;
    const int* dstp = ei + E;

    // workspace carve (256B aligned)
    char* p = (char*)d_ws;
    auto alloc = [&](size_t bytes) -> void* {
        void* r = (void*)p;
        p += (bytes + 255) & ~(size_t)255;
        return r;
    };
    int nb = (N + 255) / 256;
    int*   row_ptr   = (int*)alloc((size_t)(N + 1) * 4);
    int*   col       = (int*)alloc((size_t)E * 4);
    unsigned char* hbuf = (unsigned char*)alloc((size_t)N * 128);       // fp8 interleaved
    unsigned short* xb = (unsigned short*)alloc((size_t)N * 128 * 2);   // bf16 features
    unsigned short* xbuf = (unsigned short*)alloc((size_t)N * 64 * 2);  // final layer bf16
    float* as_       = (float*)alloc((size_t)N * 2 * 4);
    float* ad_       = (float*)alloc((size_t)N * 2 * 4);
    unsigned short* Wf1 = (unsigned short*)alloc((size_t)8 * 4 * 64 * 8 * 2);
    unsigned short* Wf2 = (unsigned short*)alloc((size_t)4 * 4 * 64 * 8 * 2);
    float* pooled    = (float*)alloc((size_t)(B * 64 + B) * 4);
    float* cnt       = pooled + (size_t)B * 64;
    // scratch (cursor + scan bookkeeping) aliases xb region: CSR build
    // completes (stream-ordered) before xb's first write (agg2, layer 0).
    int* cursor   = (int*)xb;
    int* ticket   = cursor + N;          // 1
    int* partials = ticket + 1;          // nb
    int* flags    = partials + nb;       // nb

    float* out_logits = (float*)d_out;
    float* out_value  = out_logits + (size_t)B * 16;

    // ---- CSR build: sharded count -> fused chained scan -> sharded scatter
    hipMemsetAsync(cursor, 0, (size_t)(N + 1 + 2 * nb) * 4, stream);
    int csr_V = (E + 8 * 256 - 1) / (8 * 256);
    int csr_T = csr_V * 256;
    int csr_blocks = csr_V * 8;
    count_kernel<<<csr_blocks, 256, 0, stream>>>(dstp, cursor, E, csr_T, N);
    scan_fused_kernel<<<nb, 256, 0, stream>>>(cursor, row_ptr, ticket, partials, flags, N, nb);
    scatter_kernel<<<csr_blocks, 256, 0, stream>>>(src, dstp, cursor, col, E, csr_T, N);

    // ---- fused W pack + pooled/cnt zero ----
    {
        int total = 8 * 4 * 64 + 4 * 4 * 64 + (B * 64 + B);
        pack_all_kernel<<<(total + 255) / 256, 256, 0, stream>>>(
            W1, W2, Wf1, Wf2, pooled, B * 64 + B);
    }

    // ---- GAT layer 0: in=8 -> h=[N,2,64] concat, elu ----
    transform_kernel<8, 128, 2><<<(N + 7) / 8, 128, 0, stream>>>(
        nf, W0, a_src0, a_dst0, hbuf, as_, ad_, N);
    agg2_kernel<1><<<(N + 3) / 4, 256, 0, stream>>>(
        row_ptr, col, hbuf, (const float2*)as_, (const float2*)ad_, b0, xb, N);

    // ---- GAT layer 1: in=128 -> concat, elu (MFMA transform) ----
    transform_mfma_kernel<128, 2><<<(N + 63) / 64, 256, 0, stream>>>(
        xb, Wf1, a_src1, a_dst1, hbuf, as_, ad_, N);
    agg2_kernel<1><<<(N + 3) / 4, 256, 0, stream>>>(
        row_ptr, col, hbuf, (const float2*)as_, (const float2*)ad_, b1, xb, N);

    // ---- GAT layer 2: in=128 -> heads=1, out=64 (MFMA transform) ----
    transform_mfma_kernel<64, 1><<<(N + 63) / 64, 256, 0, stream>>>(
        xb, Wf2, a_src2, a_dst2, hbuf, as_, ad_, N);
    agg1_kernel<<<(N + 3) / 4, 256, 0, stream>>>(
        row_ptr, col, hbuf, as_, ad_, b2, xbuf, N);

    // ---- mean pool + MLP head ----
    {
        int waves = (N + 15) / 16;
        int blocks = (waves + 3) / 4;
        pool_kernel<<<blocks, 256, 0, stream>>>(xbuf, batch, pooled, cnt, N);
    }
    mlp_kernel<<<B, 256, 0, stream>>>(pooled, cnt, obs, Ws1, bs1, ln_g, ln_b,
                                      Ws2, bs2, Wa, ba, Wc, bc,
                                      out_logits, out_value);
}

// Round 14
// 381.090 us; speedup vs baseline: 2.3511x; 2.3511x over previous
//
#include <hip/hip_runtime.h>
#include <math.h>

// ---------------------------------------------------------------------------
// GATPolicy: 3x GATConv (with self loops) + mean-pool + MLP head.
// CSR-by-dst via dst-range sharded count/scatter (XCD-local lines); 3-kernel
// scan (block scan -> 1-block sums scan -> finalize). NOTE r13 lesson: a
// chained/decoupled-lookback scan is ~100x slower here — cross-XCD
// release/acquire handshakes cost ~2.7us per chain link on gfx950.
// h stored FP8 e4m3 head-interleaved (byte pair at node*128+2*ch); agg inner
// loop branch-free: 3 readlane + add + ushort load + cvt_pk_f32_fp8 + 2 fma.
// Inter-layer features bf16; K=128 transforms via mfma_f32_16x16x32_bf16.
// ---------------------------------------------------------------------------

#define LRELU(x) ((x) > 0.f ? (x) : 0.2f * (x))

typedef short bf16x8 __attribute__((ext_vector_type(8)));
typedef float f32x4 __attribute__((ext_vector_type(4)));
typedef float f32x2 __attribute__((ext_vector_type(2)));

__device__ __forceinline__ float readlane_f(float v, int lane) {
    return __int_as_float(__builtin_amdgcn_readlane(__float_as_int(v), lane));
}
__device__ __forceinline__ unsigned readlane_u(unsigned v, int lane) {
    return (unsigned)__builtin_amdgcn_readlane((int)v, lane);
}
__device__ __forceinline__ unsigned short f2bf(float f) {
    unsigned int u = __float_as_uint(f);
    u = (u + 0x7fffu + ((u >> 16) & 1u)) >> 16;  // RNE
    return (unsigned short)u;
}
__device__ __forceinline__ float bf2f(unsigned short u) {
    return __uint_as_float((unsigned int)u << 16);
}
__device__ __forceinline__ unsigned char f2fp8(float f) {
    return (unsigned char)(__builtin_amdgcn_cvt_pk_fp8_f32(f, f, 0, false) & 0xff);
}
__device__ __forceinline__ f32x2 fp8pair(unsigned int u) {
    return __builtin_amdgcn_cvt_pk_f32_fp8(u, false);  // bytes 0,1
}

// ---------------- CSR build (dst-range sharded, ILP-batched) ----------------

__global__ __launch_bounds__(256) void count_kernel(
    const int* __restrict__ dst, int* __restrict__ cursor, int e, int T, int n) {
    int x = blockIdx.x & 7;
    int lo = (int)(((long long)x * n) >> 3);
    int hi = (int)(((long long)(x + 1) * n) >> 3);
    int i0 = (blockIdx.x >> 3) * 256 + threadIdx.x;
    int d[8];
#pragma unroll
    for (int j = 0; j < 8; j++) {
        int ij = i0 + j * T;
        int dd = (ij < e) ? dst[ij] : -1;
        d[j] = (dd >= lo && dd < hi) ? dd : -1;
    }
#pragma unroll
    for (int j = 0; j < 8; j++) {
        if (d[j] >= 0) atomicAdd(&cursor[d[j]], 1);
    }
}

__global__ __launch_bounds__(256) void scan_block_kernel(
    const int* __restrict__ in, int* __restrict__ out_local,
    int* __restrict__ blockSums, int n) {
    __shared__ int lds[256];
    int i = blockIdx.x * 256 + threadIdx.x;
    int v = (i < n) ? in[i] : 0;
    lds[threadIdx.x] = v;
    __syncthreads();
    for (int off = 1; off < 256; off <<= 1) {
        int t = (threadIdx.x >= off) ? lds[threadIdx.x - off] : 0;
        __syncthreads();
        lds[threadIdx.x] += t;
        __syncthreads();
    }
    if (i < n) out_local[i] = lds[threadIdx.x] - v;  // block-local exclusive
    if (threadIdx.x == 255) blockSums[blockIdx.x] = lds[255];
}

__global__ __launch_bounds__(256) void scan_sums_kernel(int* __restrict__ blockSums, int nb) {
    // nb must be <= 256
    __shared__ int lds[256];
    int v = (threadIdx.x < nb) ? blockSums[threadIdx.x] : 0;
    lds[threadIdx.x] = v;
    __syncthreads();
    for (int off = 1; off < 256; off <<= 1) {
        int t = (threadIdx.x >= off) ? lds[threadIdx.x - off] : 0;
        __syncthreads();
        lds[threadIdx.x] += t;
        __syncthreads();
    }
    if (threadIdx.x < nb) blockSums[threadIdx.x] = lds[threadIdx.x] - v;
    if (threadIdx.x == 255) blockSums[nb] = lds[255];  // total
}

__global__ void scan_finalize_kernel(int* __restrict__ row_ptr, int* __restrict__ cursor,
                                     const int* __restrict__ blockSums, int n, int nb) {
    int i = blockIdx.x * blockDim.x + threadIdx.x;
    if (i < n) {
        int v = row_ptr[i] + blockSums[i >> 8];
        row_ptr[i] = v;
        cursor[i] = v;  // write pointer for scatter
    } else if (i == n) {
        row_ptr[n] = blockSums[nb];
    }
}

__global__ __launch_bounds__(256) void scatter_kernel(
    const int* __restrict__ src, const int* __restrict__ dst,
    int* __restrict__ cursor, int* __restrict__ col, int e, int T, int n) {
    int x = blockIdx.x & 7;
    int lo = (int)(((long long)x * n) >> 3);
    int hi = (int)(((long long)(x + 1) * n) >> 3);
    int i0 = (blockIdx.x >> 3) * 256 + threadIdx.x;
    int s[8], d[8];
#pragma unroll
    for (int j = 0; j < 8; j++) {
        int ij = i0 + j * T;
        bool v = ij < e;
        int dd = v ? dst[ij] : -1;
        d[j] = (dd >= lo && dd < hi) ? dd : -1;
        s[j] = v ? src[ij] : 0;
    }
    int p[8];
#pragma unroll
    for (int j = 0; j < 8; j++) {
        p[j] = (d[j] >= 0) ? atomicAdd(&cursor[d[j]], 1) : 0;
    }
#pragma unroll
    for (int j = 0; j < 8; j++) {
        if (d[j] >= 0) col[p[j]] = s[j];
    }
}

// ---------------- fused W-pack (W1 + W2) + pooled/cnt zero -----------------

__global__ __launch_bounds__(256) void pack_all_kernel(
    const float* __restrict__ W1, const float* __restrict__ W2,
    unsigned short* __restrict__ Wf1, unsigned short* __restrict__ Wf2,
    float* __restrict__ pooled, int poolN) {
    const int n1 = 8 * 4 * 64;   // W1 fragment rows (OUT=128)
    const int n2 = 4 * 4 * 64;   // W2 fragment rows (OUT=64)
    int gid = blockIdx.x * 256 + threadIdx.x;
    if (gid < n1) {
        int idx = gid;
        int lane = idx & 63, ts = idx >> 6;
        int s = ts & 3, t = ts >> 2;
        int quad = lane >> 4, cn = lane & 15;
#pragma unroll
        for (int j = 0; j < 8; j++)
            Wf1[idx * 8 + j] = f2bf(W1[(s * 32 + quad * 8 + j) * 128 + t * 16 + cn]);
    } else if (gid < n1 + n2) {
        int idx = gid - n1;
        int lane = idx & 63, ts = idx >> 6;
        int s = ts & 3, t = ts >> 2;
        int quad = lane >> 4, cn = lane & 15;
#pragma unroll
        for (int j = 0; j < 8; j++)
            Wf2[idx * 8 + j] = f2bf(W2[(s * 32 + quad * 8 + j) * 64 + t * 16 + cn]);
    } else {
        int k = gid - n1 - n2;
        if (k < poolN) pooled[k] = 0.f;
    }
}

// fp8 h byte position for channel c: 2-head interleaved pairs, 1-head flat
template <int OUT, int HEADS>
__device__ __forceinline__ int hpos8(int c) {
    return (HEADS == 2) ? (2 * (c & 63) + (c >> 6)) : c;
}

// ---------------- layer-0 transform (K=8, VALU): h(fp8)=x@W, as/ad ---------

template <int K, int OUT, int HEADS>
__global__ __launch_bounds__(OUT) void transform_kernel(
    const float* __restrict__ x, const float* __restrict__ W,
    const float* __restrict__ a_src, const float* __restrict__ a_dst,
    unsigned char* __restrict__ h, float* __restrict__ as_o, float* __restrict__ ad_o,
    int n) {
    constexpr int NPB = 8;
    __shared__ float xs[NPB][K];
    const int tid = threadIdx.x;
    const int node0 = blockIdx.x * NPB;

    for (int idx = tid; idx < NPB * K; idx += OUT) {
        int ni = idx / K, k = idx - ni * K;
        int ng = node0 + ni;
        xs[ni][k] = (ng < n) ? x[(size_t)ng * K + k] : 0.f;
    }
    __syncthreads();

    float acc[NPB];
#pragma unroll
    for (int i = 0; i < NPB; i++) acc[i] = 0.f;
    for (int k = 0; k < K; k++) {
        float wk = W[k * OUT + tid];
#pragma unroll
        for (int i = 0; i < NPB; i++) acc[i] += xs[i][k] * wk;
    }

    const int lane = tid & 63;
    const int head = (HEADS == 2) ? (tid >> 6) : 0;
    const int pos = hpos8<OUT, HEADS>(tid);
    const float av = a_src[tid];
    const float dv = a_dst[tid];
#pragma unroll
    for (int i = 0; i < NPB; i++) {
        int ng = node0 + i;
        if (ng >= n) break;
        h[(size_t)ng * OUT + pos] = f2fp8(acc[i]);
        float ps = acc[i] * av, pd = acc[i] * dv;
        for (int off = 32; off; off >>= 1) {
            ps += __shfl_xor(ps, off, 64);
            pd += __shfl_xor(pd, off, 64);
        }
        if (lane == 0) {
            as_o[ng * HEADS + head] = ps;
            ad_o[ng * HEADS + head] = pd;
        }
    }
}

// ---------------- MFMA transform (K=128): h(fp8)=xb(bf16)@W, as/ad ---------

template <int OUT, int HEADS>
__global__ __launch_bounds__(256) void transform_mfma_kernel(
    const unsigned short* __restrict__ xb, const unsigned short* __restrict__ Wf,
    const float* __restrict__ a_src, const float* __restrict__ a_dst,
    unsigned char* __restrict__ h, float* __restrict__ as_o, float* __restrict__ ad_o,
    int n) {
    constexpr int T = OUT / 16, S = 4;  // K = 128
    const int w = threadIdx.x >> 6, lane = threadIdx.x & 63;
    const int node0 = (blockIdx.x * 4 + w) * 16;
    if (node0 >= n) return;
    const int quad = lane >> 4, col = lane & 15;

    const int arow = node0 + col;
    const bool aok = arow < n;
    bf16x8 a[S];
    const unsigned short* xrow = xb + (size_t)arow * 128 + quad * 8;
#pragma unroll
    for (int s = 0; s < S; s++) {
        bf16x8 z = {0, 0, 0, 0, 0, 0, 0, 0};
        a[s] = aok ? *(const bf16x8*)(xrow + s * 32) : z;
    }

    f32x4 acc[T];
#pragma unroll
    for (int t = 0; t < T; t++) acc[t] = (f32x4){0.f, 0.f, 0.f, 0.f};

#pragma unroll
    for (int s = 0; s < S; s++) {
#pragma unroll
        for (int t = 0; t < T; t++) {
            bf16x8 b = *(const bf16x8*)(Wf + ((size_t)(t * S + s) * 64 + lane) * 8);
            acc[t] = __builtin_amdgcn_mfma_f32_16x16x32_bf16(a[s], b, acc[t], 0, 0, 0);
        }
    }

#pragma unroll
    for (int t = 0; t < T; t++) {
        int pos = hpos8<OUT, HEADS>(t * 16 + col);
#pragma unroll
        for (int r = 0; r < 4; r++) {
            int m = node0 + quad * 4 + r;
            if (m < n) h[(size_t)m * OUT + pos] = f2fp8(acc[t][r]);
        }
    }

#pragma unroll
    for (int r = 0; r < 4; r++) {
        float s0 = 0.f, s1 = 0.f, d0 = 0.f, d1 = 0.f;
#pragma unroll
        for (int t = 0; t < T; t++) {
            float av = a_src[t * 16 + col];
            float dv = a_dst[t * 16 + col];
            float v = acc[t][r];
            if (HEADS == 2 && t >= T / 2) { s1 += v * av; d1 += v * dv; }
            else                          { s0 += v * av; d0 += v * dv; }
        }
        for (int off = 8; off; off >>= 1) {
            s0 += __shfl_xor(s0, off, 64);
            d0 += __shfl_xor(d0, off, 64);
            if (HEADS == 2) {
                s1 += __shfl_xor(s1, off, 64);
                d1 += __shfl_xor(d1, off, 64);
            }
        }
        int m = node0 + quad * 4 + r;
        if (m < n) {
            if (HEADS == 2) {
                if (col == 0)      { as_o[m * 2] = s0;     ad_o[m * 2] = d0; }
                else if (col == 1) { as_o[m * 2 + 1] = s1; ad_o[m * 2 + 1] = d1; }
            } else {
                if (col == 0) { as_o[m] = s0; ad_o[m] = d0; }
            }
        }
    }
}

// ---------------- GAT aggregation, 2 heads (fp8 h): one wave per node ------

template <int ACT>  // 1 = elu
__global__ __launch_bounds__(256) void agg2_kernel(
    const int* __restrict__ row_ptr, const int* __restrict__ col,
    const unsigned char* __restrict__ h, const float2* __restrict__ as2,
    const float2* __restrict__ ad2, const float* __restrict__ bias,
    unsigned short* __restrict__ out, int n) {
    const int node = blockIdx.x * 4 + (threadIdx.x >> 6);
    const int lane = threadIdx.x & 63;
    if (node >= n) return;

    const int beg = row_ptr[node], end = row_ptr[node + 1];
    const float2 adv = ad2[node];
    const unsigned char* __restrict__ hb = h + 2 * lane;

    // self-loop
    const float2 avs = as2[node];
    float w0s = __expf(LRELU(avs.x + adv.x));
    float w1s = __expf(LRELU(avs.y + adv.y));
    unsigned int us = *(const unsigned short*)(hb + ((size_t)node << 7));
    f32x2 hvs = fp8pair(us);
    float accL = w0s * hvs.x, accH = w1s * hvs.y;
    float den0 = w0s, den1 = w1s;

    for (int base = beg; base < end; base += 64) {
        int cnt = end - base;
        if (cnt > 64) cnt = 64;
        int s = 0;
        float w0 = 0.f, w1 = 0.f;
        if (lane < cnt) {
            s = col[base + lane];
            float2 av = as2[s];
            w0 = __expf(LRELU(av.x + adv.x));
            w1 = __expf(LRELU(av.y + adv.y));
        }
        float t0 = w0, t1 = w1;
        for (int off = 32; off; off >>= 1) {
            t0 += __shfl_xor(t0, off, 64);
            t1 += __shfl_xor(t1, off, 64);
        }
        den0 += t0;
        den1 += t1;

        unsigned soff = (unsigned)s << 7;  // row byte offset (128 B)
        for (int j = 0; j < cnt; j += 4) {  // j <= 60; pads carry w=0
            unsigned oA = readlane_u(soff, j);
            unsigned oB = readlane_u(soff, j + 1);
            unsigned oC = readlane_u(soff, j + 2);
            unsigned oD = readlane_u(soff, j + 3);
            float a0 = readlane_f(w0, j),     a1 = readlane_f(w1, j);
            float b0 = readlane_f(w0, j + 1), b1 = readlane_f(w1, j + 1);
            float c0 = readlane_f(w0, j + 2), c1 = readlane_f(w1, j + 2);
            float d0 = readlane_f(w0, j + 3), d1 = readlane_f(w1, j + 3);
            unsigned uA = *(const unsigned short*)(hb + oA);
            unsigned uB = *(const unsigned short*)(hb + oB);
            unsigned uC = *(const unsigned short*)(hb + oC);
            unsigned uD = *(const unsigned short*)(hb + oD);
            f32x2 hA = fp8pair(uA);
            f32x2 hB = fp8pair(uB);
            f32x2 hC = fp8pair(uC);
            f32x2 hD = fp8pair(uD);
            accL += a0 * hA.x; accH += a1 * hA.y;
            accL += b0 * hB.x; accH += b1 * hB.y;
            accL += c0 * hC.x; accH += c1 * hC.y;
            accL += d0 * hD.x; accH += d1 * hD.y;
        }
    }

    float oL = accL / (den0 + 1e-16f) + bias[lane];
    float oH = accH / (den1 + 1e-16f) + bias[64 + lane];
    if (ACT) {
        oL = oL > 0.f ? oL : expm1f(oL);
        oH = oH > 0.f ? oH : expm1f(oH);
    }
    out[(size_t)node * 128 + lane] = f2bf(oL);
    out[(size_t)node * 128 + 64 + lane] = f2bf(oH);
}

// ---------------- GAT aggregation, 1 head (fp8 h, layer 2) -----------------
// Output bf16 (feeds pool only).

__global__ __launch_bounds__(256) void agg1_kernel(
    const int* __restrict__ row_ptr, const int* __restrict__ col,
    const unsigned char* __restrict__ h, const float* __restrict__ as1,
    const float* __restrict__ ad1, const float* __restrict__ bias,
    unsigned short* __restrict__ out, int n) {
    const int node = blockIdx.x * 4 + (threadIdx.x >> 6);
    const int lane = threadIdx.x & 63;
    if (node >= n) return;

    const int beg = row_ptr[node], end = row_ptr[node + 1];
    const float adv = ad1[node];
    const unsigned char* __restrict__ hb = h + lane;

    float ws = __expf(LRELU(as1[node] + adv));
    float acc = ws * fp8pair((unsigned)hb[(size_t)node << 6]).x;
    float den = ws;

    for (int base = beg; base < end; base += 64) {
        int cnt = end - base;
        if (cnt > 64) cnt = 64;
        int s = 0;
        float w = 0.f;
        if (lane < cnt) {
            s = col[base + lane];
            w = __expf(LRELU(as1[s] + adv));
        }
        float t = w;
        for (int off = 32; off; off >>= 1) t += __shfl_xor(t, off, 64);
        den += t;

        unsigned soff = (unsigned)s << 6;  // row byte offset (64 B)
        for (int j = 0; j < cnt; j += 4) {
            unsigned oA = readlane_u(soff, j);
            unsigned oB = readlane_u(soff, j + 1);
            unsigned oC = readlane_u(soff, j + 2);
            unsigned oD = readlane_u(soff, j + 3);
            float wA = readlane_f(w, j);
            float wB = readlane_f(w, j + 1);
            float wC = readlane_f(w, j + 2);
            float wD = readlane_f(w, j + 3);
            float hA = fp8pair((unsigned)hb[oA]).x;
            float hB = fp8pair((unsigned)hb[oB]).x;
            float hC = fp8pair((unsigned)hb[oC]).x;
            float hD = fp8pair((unsigned)hb[oD]).x;
            acc += wA * hA;
            acc += wB * hB;
            acc += wC * hC;
            acc += wD * hD;
        }
    }

    out[(size_t)node * 64 + lane] = f2bf(acc / (den + 1e-16f) + bias[lane]);
}

// ---------------- mean pool over sorted batch (bf16 in) --------------------

__global__ __launch_bounds__(256) void pool_kernel(
    const unsigned short* __restrict__ x, const int* __restrict__ batch,
    float* __restrict__ pooled, float* __restrict__ cnt, int n) {
    const int NPW = 16;
    int wid = blockIdx.x * (blockDim.x >> 6) + (threadIdx.x >> 6);
    int lane = threadIdx.x & 63;
    int start = wid * NPW;
    if (start >= n) return;
    int end = min(start + NPW, n);
    float acc = 0.f, c = 0.f;
    int cur = -1;
    for (int i = start; i < end; i++) {
        int b = batch[i];
        if (b != cur) {
            if (cur >= 0) {
                atomicAdd(&pooled[cur * 64 + lane], acc);
                if (lane == 0) atomicAdd(&cnt[cur], c);
            }
            cur = b;
            acc = 0.f;
            c = 0.f;
        }
        acc += bf2f(x[(size_t)i * 64 + lane]);
        c += 1.f;
    }
    if (cur >= 0) {
        atomicAdd(&pooled[cur * 64 + lane], acc);
        if (lane == 0) atomicAdd(&cnt[cur], c);
    }
}

// ---------------- MLP head: one block per graph row ------------------------

__global__ __launch_bounds__(256) void mlp_kernel(
    const float* __restrict__ pooled, const float* __restrict__ cnt,
    const float* __restrict__ obs,
    const float* __restrict__ Ws1, const float* __restrict__ bs1,
    const float* __restrict__ ln_g, const float* __restrict__ ln_b,
    const float* __restrict__ Ws2, const float* __restrict__ bs2,
    const float* __restrict__ Wa, const float* __restrict__ ba,
    const float* __restrict__ Wc, const float* __restrict__ bc,
    float* __restrict__ out_logits, float* __restrict__ out_value) {
    int b = blockIdx.x;
    int t = threadIdx.x;
    __shared__ float comb[192];
    __shared__ float red[256];
    __shared__ float hs[256];

    if (t < 64) {
        float c = cnt[b];
        c = c > 1.f ? c : 1.f;
        comb[t] = pooled[b * 64 + t] / c;
    } else if (t < 192) {
        comb[t] = obs[b * 128 + (t - 64)];
    }
    __syncthreads();

    float acc = bs1[t];
    for (int k = 0; k < 192; k++) acc += comb[k] * Ws1[k * 256 + t];

    red[t] = acc;
    __syncthreads();
    for (int off = 128; off; off >>= 1) {
        if (t < off) red[t] += red[t + off];
        __syncthreads();
    }
    float mu = red[0] / 256.f;
    __syncthreads();
    float d = acc - mu;
    red[t] = d * d;
    __syncthreads();
    for (int off = 128; off; off >>= 1) {
        if (t < off) red[t] += red[t + off];
        __syncthreads();
    }
    float var = red[0] / 256.f;
    float hn = d * rsqrtf(var + 1e-5f) * ln_g[t] + ln_b[t];
    hn = hn > 0.f ? hn : 0.f;
    __syncthreads();
    hs[t] = hn;
    __syncthreads();

    float acc2 = bs2[t];
    for (int k = 0; k < 256; k++) acc2 += hs[k] * Ws2[k * 256 + t];
    acc2 = acc2 > 0.f ? acc2 : 0.f;
    __syncthreads();
    hs[t] = acc2;
    __syncthreads();

    if (t < 16) {
        float a = ba[t];
        for (int k = 0; k < 256; k++) a += hs[k] * Wa[k * 16 + t];
        out_logits[b * 16 + t] = a;
    } else if (t == 16) {
        float v = bc[0];
        for (int k = 0; k < 256; k++) v += hs[k] * Wc[k];
        out_value[b] = v;
    }
}

// ---------------------------------------------------------------------------

extern "C" void kernel_launch(void* const* d_in, const int* in_sizes, int n_in,
                              void* d_out, int out_size, void* d_ws, size_t ws_size,
                              hipStream_t stream) {
    const float* obs    = (const float*)d_in[0];
    const float* nf     = (const float*)d_in[1];
    const int*   ei     = (const int*)d_in[2];
    const int*   batch  = (const int*)d_in[3];
    const float* W0     = (const float*)d_in[4];
    const float* a_src0 = (const float*)d_in[5];
    const float* a_dst0 = (const float*)d_in[6];
    const float* b0     = (const float*)d_in[7];
    const float* W1     = (const float*)d_in[8];
    const float* a_src1 = (const float*)d_in[9];
    const float* a_dst1 = (const float*)d_in[10];
    const float* b1     = (const float*)d_in[11];
    const float* W2     = (const float*)d_in[12];
    const float* a_src2 = (const float*)d_in[13];
    const float* a_dst2 = (const float*)d_in[14];
    const float* b2     = (const float*)d_in[15];
    const float* Ws1    = (const float*)d_in[16];
    const float* bs1    = (const float*)d_in[17];
    const float* ln_g   = (const float*)d_in[18];
    const float* ln_b   = (const float*)d_in[19];
    const float* Ws2    = (const float*)d_in[20];
    const float* bs2    = (const float*)d_in[21];
    const float* Wa     = (const float*)d_in[22];
    const float* ba     = (const float*)d_in[23];
    const float* Wc     = (const float*)d_in[24];
    const float* bc     = (const float*)d_in[25];

    const int N = in_sizes[3];
    const int E = in_sizes[2] / 2;
    const int B = in_sizes[0] / 128;
    const int* src = ei;
    const int* dstp = ei + E;

    // workspace carve (256B aligned)
    char* p = (char*)d_ws;
    auto alloc = [&](size_t bytes) -> void* {
        void* r = (void*)p;
        p += (bytes + 255) & ~(size_t)255;
        return r;
    };
    int nb = (N + 255) / 256;
    int*   row_ptr   = (int*)alloc((size_t)(N + 1) * 4);
    int*   col       = (int*)alloc((size_t)E * 4);
    unsigned char* hbuf = (unsigned char*)alloc((size_t)N * 128);       // fp8 interleaved
    unsigned short* xb = (unsigned short*)alloc((size_t)N * 128 * 2);   // bf16 features
    unsigned short* xbuf = (unsigned short*)alloc((size_t)N * 64 * 2);  // final layer bf16
    float* as_       = (float*)alloc((size_t)N * 2 * 4);
    float* ad_       = (float*)alloc((size_t)N * 2 * 4);
    unsigned short* Wf1 = (unsigned short*)alloc((size_t)8 * 4 * 64 * 8 * 2);
    unsigned short* Wf2 = (unsigned short*)alloc((size_t)4 * 4 * 64 * 8 * 2);
    float* pooled    = (float*)alloc((size_t)(B * 64 + B) * 4);
    float* cnt       = pooled + (size_t)B * 64;
    // scratch (cursor + blockSums) aliases xb region: CSR build completes
    // (stream-ordered) before xb's first write (agg2, layer 0).
    int* cursor    = (int*)xb;
    int* blockSums = cursor + N;         // nb + 1

    float* out_logits = (float*)d_out;
    float* out_value  = out_logits + (size_t)B * 16;

    // ---- CSR build: sharded count -> 3-kernel scan -> sharded scatter ----
    hipMemsetAsync(cursor, 0, (size_t)N * 4, stream);
    int csr_V = (E + 8 * 256 - 1) / (8 * 256);
    int csr_T = csr_V * 256;
    int csr_blocks = csr_V * 8;
    count_kernel<<<csr_blocks, 256, 0, stream>>>(dstp, cursor, E, csr_T, N);
    scan_block_kernel<<<nb, 256, 0, stream>>>(cursor, row_ptr, blockSums, N);
    scan_sums_kernel<<<1, 256, 0, stream>>>(blockSums, nb);
    scan_finalize_kernel<<<(N + 1 + 255) / 256, 256, 0, stream>>>(row_ptr, cursor, blockSums, N, nb);
    scatter_kernel<<<csr_blocks, 256, 0, stream>>>(src, dstp, cursor, col, E, csr_T, N);

    // ---- fused W pack + pooled/cnt zero ----
    {
        int total = 8 * 4 * 64 + 4 * 4 * 64 + (B * 64 + B);
        pack_all_kernel<<<(total + 255) / 256, 256, 0, stream>>>(
            W1, W2, Wf1, Wf2, pooled, B * 64 + B);
    }

    // ---- GAT layer 0: in=8 -> h=[N,2,64] concat, elu ----
    transform_kernel<8, 128, 2><<<(N + 7) / 8, 128, 0, stream>>>(
        nf, W0, a_src0, a_dst0, hbuf, as_, ad_, N);
    agg2_kernel<1><<<(N + 3) / 4, 256, 0, stream>>>(
        row_ptr, col, hbuf, (const float2*)as_, (const float2*)ad_, b0, xb, N);

    // ---- GAT layer 1: in=128 -> concat, elu (MFMA transform) ----
    transform_mfma_kernel<128, 2><<<(N + 63) / 64, 256, 0, stream>>>(
        xb, Wf1, a_src1, a_dst1, hbuf, as_, ad_, N);
    agg2_kernel<1><<<(N + 3) / 4, 256, 0, stream>>>(
        row_ptr, col, hbuf, (const float2*)as_, (const float2*)ad_, b1, xb, N);

    // ---- GAT layer 2: in=128 -> heads=1, out=64 (MFMA transform) ----
    transform_mfma_kernel<64, 1><<<(N + 63) / 64, 256, 0, stream>>>(
        xb, Wf2, a_src2, a_dst2, hbuf, as_, ad_, N);
    agg1_kernel<<<(N + 3) / 4, 256, 0, stream>>>(
        row_ptr, col, hbuf, as_, ad_, b2, xbuf, N);

    // ---- mean pool + MLP head ----
    {
        int waves = (N + 15) / 16;
        int blocks = (waves + 3) / 4;
        pool_kernel<<<blocks, 256, 0, stream>>>(xbuf, batch, pooled, cnt, N);
    }
    mlp_kernel<<<B, 256, 0, stream>>>(pooled, cnt, obs, Ws1, bs1, ln_g, ln_b,
                                      Ws2, bs2, Wa, ba, Wc, bc,
                                      out_logits, out_value);
}

// Round 15
// 357.929 us; speedup vs baseline: 2.5032x; 1.0647x over previous
//
#include <hip/hip_runtime.h>
#include <math.h>

// ---------------------------------------------------------------------------
// GATPolicy: 3x GATConv (with self loops) + mean-pool + MLP head.
// CSR-by-dst via dst-range sharded count/scatter (XCD-local lines); 3-kernel
// scan. Scatter is ATOMIC-FREE: count's atomicAdd return value is the edge's
// rank within its row (only one shard touches a row), stored to rank[e];
// scatter does col[row_ptr[dst]+rank] = src. (r13 lesson: never chain blocks
// across XCDs — cross-XCD release/acquire costs ~2.7us per link.)
// h stored FP8 e4m3 head-interleaved (byte pair at node*128+2*ch); agg inner
// loop branch-free: 3 readlane + add + ushort load + cvt_pk_f32_fp8 + 2 fma.
// Inter-layer features bf16; K=128 transforms via mfma_f32_16x16x32_bf16.
// ---------------------------------------------------------------------------

#define LRELU(x) ((x) > 0.f ? (x) : 0.2f * (x))

typedef short bf16x8 __attribute__((ext_vector_type(8)));
typedef float f32x4 __attribute__((ext_vector_type(4)));
typedef float f32x2 __attribute__((ext_vector_type(2)));

__device__ __forceinline__ float readlane_f(float v, int lane) {
    return __int_as_float(__builtin_amdgcn_readlane(__float_as_int(v), lane));
}
__device__ __forceinline__ unsigned readlane_u(unsigned v, int lane) {
    return (unsigned)__builtin_amdgcn_readlane((int)v, lane);
}
__device__ __forceinline__ unsigned short f2bf(float f) {
    unsigned int u = __float_as_uint(f);
    u = (u + 0x7fffu + ((u >> 16) & 1u)) >> 16;  // RNE
    return (unsigned short)u;
}
__device__ __forceinline__ float bf2f(unsigned short u) {
    return __uint_as_float((unsigned int)u << 16);
}
__device__ __forceinline__ unsigned char f2fp8(float f) {
    return (unsigned char)(__builtin_amdgcn_cvt_pk_fp8_f32(f, f, 0, false) & 0xff);
}
__device__ __forceinline__ f32x2 fp8pair(unsigned int u) {
    return __builtin_amdgcn_cvt_pk_f32_fp8(u, false);  // bytes 0,1
}

// ---------------- CSR build (dst-range sharded, ILP-batched) ----------------
// count: atomicAdd returns the edge's rank within its row (one shard per row);
// stored to rank[] so scatter needs no atomics.

__global__ __launch_bounds__(256) void count_kernel(
    const int* __restrict__ dst, int* __restrict__ cursor,
    int* __restrict__ rank, int e, int T, int n) {
    int x = blockIdx.x & 7;
    int lo = (int)(((long long)x * n) >> 3);
    int hi = (int)(((long long)(x + 1) * n) >> 3);
    int i0 = (blockIdx.x >> 3) * 256 + threadIdx.x;
    int ij[8], d[8];
#pragma unroll
    for (int j = 0; j < 8; j++) {
        ij[j] = i0 + j * T;
        int dd = (ij[j] < e) ? dst[ij[j]] : -1;
        d[j] = (dd >= lo && dd < hi) ? dd : -1;
    }
    int r[8];
#pragma unroll
    for (int j = 0; j < 8; j++) {
        r[j] = (d[j] >= 0) ? atomicAdd(&cursor[d[j]], 1) : 0;
    }
#pragma unroll
    for (int j = 0; j < 8; j++) {
        if (d[j] >= 0) rank[ij[j]] = r[j];
    }
}

__global__ __launch_bounds__(256) void scan_block_kernel(
    const int* __restrict__ in, int* __restrict__ out_local,
    int* __restrict__ blockSums, int n) {
    __shared__ int lds[256];
    int i = blockIdx.x * 256 + threadIdx.x;
    int v = (i < n) ? in[i] : 0;
    lds[threadIdx.x] = v;
    __syncthreads();
    for (int off = 1; off < 256; off <<= 1) {
        int t = (threadIdx.x >= off) ? lds[threadIdx.x - off] : 0;
        __syncthreads();
        lds[threadIdx.x] += t;
        __syncthreads();
    }
    if (i < n) out_local[i] = lds[threadIdx.x] - v;  // block-local exclusive
    if (threadIdx.x == 255) blockSums[blockIdx.x] = lds[255];
}

__global__ __launch_bounds__(256) void scan_sums_kernel(int* __restrict__ blockSums, int nb) {
    // nb must be <= 256
    __shared__ int lds[256];
    int v = (threadIdx.x < nb) ? blockSums[threadIdx.x] : 0;
    lds[threadIdx.x] = v;
    __syncthreads();
    for (int off = 1; off < 256; off <<= 1) {
        int t = (threadIdx.x >= off) ? lds[threadIdx.x - off] : 0;
        __syncthreads();
        lds[threadIdx.x] += t;
        __syncthreads();
    }
    if (threadIdx.x < nb) blockSums[threadIdx.x] = lds[threadIdx.x] - v;
    if (threadIdx.x == 255) blockSums[nb] = lds[255];  // total
}

__global__ void scan_finalize_kernel(int* __restrict__ row_ptr,
                                     const int* __restrict__ blockSums, int n, int nb) {
    int i = blockIdx.x * blockDim.x + threadIdx.x;
    if (i < n) {
        row_ptr[i] += blockSums[i >> 8];
    } else if (i == n) {
        row_ptr[n] = blockSums[nb];
    }
}

// Atomic-free: col[row_ptr[dst] + rank] = src. Sharded so col writes for a
// row come from one XCD (shard = pure function of dst value).
__global__ __launch_bounds__(256) void scatter_kernel(
    const int* __restrict__ src, const int* __restrict__ dst,
    const int* __restrict__ row_ptr, const int* __restrict__ rank,
    int* __restrict__ col, int e, int T, int n) {
    int x = blockIdx.x & 7;
    int lo = (int)(((long long)x * n) >> 3);
    int hi = (int)(((long long)(x + 1) * n) >> 3);
    int i0 = (blockIdx.x >> 3) * 256 + threadIdx.x;
    int s[8], d[8], r[8];
#pragma unroll
    for (int j = 0; j < 8; j++) {
        int ij = i0 + j * T;
        bool v = ij < e;
        int dd = v ? dst[ij] : -1;
        d[j] = (dd >= lo && dd < hi) ? dd : -1;
        s[j] = v ? src[ij] : 0;
        r[j] = v ? rank[ij] : 0;
    }
    int p[8];
#pragma unroll
    for (int j = 0; j < 8; j++) {
        p[j] = (d[j] >= 0) ? row_ptr[d[j]] + r[j] : 0;
    }
#pragma unroll
    for (int j = 0; j < 8; j++) {
        if (d[j] >= 0) col[p[j]] = s[j];
    }
}

// ---------------- fused W-pack (W1 + W2) + pooled/cnt zero -----------------

__global__ __launch_bounds__(256) void pack_all_kernel(
    const float* __restrict__ W1, const float* __restrict__ W2,
    unsigned short* __restrict__ Wf1, unsigned short* __restrict__ Wf2,
    float* __restrict__ pooled, int poolN) {
    const int n1 = 8 * 4 * 64;   // W1 fragment rows (OUT=128)
    const int n2 = 4 * 4 * 64;   // W2 fragment rows (OUT=64)
    int gid = blockIdx.x * 256 + threadIdx.x;
    if (gid < n1) {
        int idx = gid;
        int lane = idx & 63, ts = idx >> 6;
        int s = ts & 3, t = ts >> 2;
        int quad = lane >> 4, cn = lane & 15;
#pragma unroll
        for (int j = 0; j < 8; j++)
            Wf1[idx * 8 + j] = f2bf(W1[(s * 32 + quad * 8 + j) * 128 + t * 16 + cn]);
    } else if (gid < n1 + n2) {
        int idx = gid - n1;
        int lane = idx & 63, ts = idx >> 6;
        int s = ts & 3, t = ts >> 2;
        int quad = lane >> 4, cn = lane & 15;
#pragma unroll
        for (int j = 0; j < 8; j++)
            Wf2[idx * 8 + j] = f2bf(W2[(s * 32 + quad * 8 + j) * 64 + t * 16 + cn]);
    } else {
        int k = gid - n1 - n2;
        if (k < poolN) pooled[k] = 0.f;
    }
}

// fp8 h byte position for channel c: 2-head interleaved pairs, 1-head flat
template <int OUT, int HEADS>
__device__ __forceinline__ int hpos8(int c) {
    return (HEADS == 2) ? (2 * (c & 63) + (c >> 6)) : c;
}

// ---------------- layer-0 transform (K=8, VALU): h(fp8)=x@W, as/ad ---------

template <int K, int OUT, int HEADS>
__global__ __launch_bounds__(OUT) void transform_kernel(
    const float* __restrict__ x, const float* __restrict__ W,
    const float* __restrict__ a_src, const float* __restrict__ a_dst,
    unsigned char* __restrict__ h, float* __restrict__ as_o, float* __restrict__ ad_o,
    int n) {
    constexpr int NPB = 8;
    __shared__ float xs[NPB][K];
    const int tid = threadIdx.x;
    const int node0 = blockIdx.x * NPB;

    for (int idx = tid; idx < NPB * K; idx += OUT) {
        int ni = idx / K, k = idx - ni * K;
        int ng = node0 + ni;
        xs[ni][k] = (ng < n) ? x[(size_t)ng * K + k] : 0.f;
    }
    __syncthreads();

    float acc[NPB];
#pragma unroll
    for (int i = 0; i < NPB; i++) acc[i] = 0.f;
    for (int k = 0; k < K; k++) {
        float wk = W[k * OUT + tid];
#pragma unroll
        for (int i = 0; i < NPB; i++) acc[i] += xs[i][k] * wk;
    }

    const int lane = tid & 63;
    const int head = (HEADS == 2) ? (tid >> 6) : 0;
    const int pos = hpos8<OUT, HEADS>(tid);
    const float av = a_src[tid];
    const float dv = a_dst[tid];
#pragma unroll
    for (int i = 0; i < NPB; i++) {
        int ng = node0 + i;
        if (ng >= n) break;
        h[(size_t)ng * OUT + pos] = f2fp8(acc[i]);
        float ps = acc[i] * av, pd = acc[i] * dv;
        for (int off = 32; off; off >>= 1) {
            ps += __shfl_xor(ps, off, 64);
            pd += __shfl_xor(pd, off, 64);
        }
        if (lane == 0) {
            as_o[ng * HEADS + head] = ps;
            ad_o[ng * HEADS + head] = pd;
        }
    }
}

// ---------------- MFMA transform (K=128): h(fp8)=xb(bf16)@W, as/ad ---------

template <int OUT, int HEADS>
__global__ __launch_bounds__(256) void transform_mfma_kernel(
    const unsigned short* __restrict__ xb, const unsigned short* __restrict__ Wf,
    const float* __restrict__ a_src, const float* __restrict__ a_dst,
    unsigned char* __restrict__ h, float* __restrict__ as_o, float* __restrict__ ad_o,
    int n) {
    constexpr int T = OUT / 16, S = 4;  // K = 128
    const int w = threadIdx.x >> 6, lane = threadIdx.x & 63;
    const int node0 = (blockIdx.x * 4 + w) * 16;
    if (node0 >= n) return;
    const int quad = lane >> 4, col = lane & 15;

    const int arow = node0 + col;
    const bool aok = arow < n;
    bf16x8 a[S];
    const unsigned short* xrow = xb + (size_t)arow * 128 + quad * 8;
#pragma unroll
    for (int s = 0; s < S; s++) {
        bf16x8 z = {0, 0, 0, 0, 0, 0, 0, 0};
        a[s] = aok ? *(const bf16x8*)(xrow + s * 32) : z;
    }

    f32x4 acc[T];
#pragma unroll
    for (int t = 0; t < T; t++) acc[t] = (f32x4){0.f, 0.f, 0.f, 0.f};

#pragma unroll
    for (int s = 0; s < S; s++) {
#pragma unroll
        for (int t = 0; t < T; t++) {
            bf16x8 b = *(const bf16x8*)(Wf + ((size_t)(t * S + s) * 64 + lane) * 8);
            acc[t] = __builtin_amdgcn_mfma_f32_16x16x32_bf16(a[s], b, acc[t], 0, 0, 0);
        }
    }

#pragma unroll
    for (int t = 0; t < T; t++) {
        int pos = hpos8<OUT, HEADS>(t * 16 + col);
#pragma unroll
        for (int r = 0; r < 4; r++) {
            int m = node0 + quad * 4 + r;
            if (m < n) h[(size_t)m * OUT + pos] = f2fp8(acc[t][r]);
        }
    }

#pragma unroll
    for (int r = 0; r < 4; r++) {
        float s0 = 0.f, s1 = 0.f, d0 = 0.f, d1 = 0.f;
#pragma unroll
        for (int t = 0; t < T; t++) {
            float av = a_src[t * 16 + col];
            float dv = a_dst[t * 16 + col];
            float v = acc[t][r];
            if (HEADS == 2 && t >= T / 2) { s1 += v * av; d1 += v * dv; }
            else                          { s0 += v * av; d0 += v * dv; }
        }
        for (int off = 8; off; off >>= 1) {
            s0 += __shfl_xor(s0, off, 64);
            d0 += __shfl_xor(d0, off, 64);
            if (HEADS == 2) {
                s1 += __shfl_xor(s1, off, 64);
                d1 += __shfl_xor(d1, off, 64);
            }
        }
        int m = node0 + quad * 4 + r;
        if (m < n) {
            if (HEADS == 2) {
                if (col == 0)      { as_o[m * 2] = s0;     ad_o[m * 2] = d0; }
                else if (col == 1) { as_o[m * 2 + 1] = s1; ad_o[m * 2 + 1] = d1; }
            } else {
                if (col == 0) { as_o[m] = s0; ad_o[m] = d0; }
            }
        }
    }
}

// ---------------- GAT aggregation, 2 heads (fp8 h): one wave per node ------

template <int ACT>  // 1 = elu
__global__ __launch_bounds__(256) void agg2_kernel(
    const int* __restrict__ row_ptr, const int* __restrict__ col,
    const unsigned char* __restrict__ h, const float2* __restrict__ as2,
    const float2* __restrict__ ad2, const float* __restrict__ bias,
    unsigned short* __restrict__ out, int n) {
    const int node = blockIdx.x * 4 + (threadIdx.x >> 6);
    const int lane = threadIdx.x & 63;
    if (node >= n) return;

    const int beg = row_ptr[node], end = row_ptr[node + 1];
    const float2 adv = ad2[node];
    const unsigned char* __restrict__ hb = h + 2 * lane;

    // self-loop
    const float2 avs = as2[node];
    float w0s = __expf(LRELU(avs.x + adv.x));
    float w1s = __expf(LRELU(avs.y + adv.y));
    unsigned int us = *(const unsigned short*)(hb + ((size_t)node << 7));
    f32x2 hvs = fp8pair(us);
    float accL = w0s * hvs.x, accH = w1s * hvs.y;
    float den0 = w0s, den1 = w1s;

    for (int base = beg; base < end; base += 64) {
        int cnt = end - base;
        if (cnt > 64) cnt = 64;
        int s = 0;
        float w0 = 0.f, w1 = 0.f;
        if (lane < cnt) {
            s = col[base + lane];
            float2 av = as2[s];
            w0 = __expf(LRELU(av.x + adv.x));
            w1 = __expf(LRELU(av.y + adv.y));
        }
        float t0 = w0, t1 = w1;
        for (int off = 32; off; off >>= 1) {
            t0 += __shfl_xor(t0, off, 64);
            t1 += __shfl_xor(t1, off, 64);
        }
        den0 += t0;
        den1 += t1;

        unsigned soff = (unsigned)s << 7;  // row byte offset (128 B)
        for (int j = 0; j < cnt; j += 4) {  // j <= 60; pads carry w=0
            unsigned oA = readlane_u(soff, j);
            unsigned oB = readlane_u(soff, j + 1);
            unsigned oC = readlane_u(soff, j + 2);
            unsigned oD = readlane_u(soff, j + 3);
            float a0 = readlane_f(w0, j),     a1 = readlane_f(w1, j);
            float b0 = readlane_f(w0, j + 1), b1 = readlane_f(w1, j + 1);
            float c0 = readlane_f(w0, j + 2), c1 = readlane_f(w1, j + 2);
            float d0 = readlane_f(w0, j + 3), d1 = readlane_f(w1, j + 3);
            unsigned uA = *(const unsigned short*)(hb + oA);
            unsigned uB = *(const unsigned short*)(hb + oB);
            unsigned uC = *(const unsigned short*)(hb + oC);
            unsigned uD = *(const unsigned short*)(hb + oD);
            f32x2 hA = fp8pair(uA);
            f32x2 hB = fp8pair(uB);
            f32x2 hC = fp8pair(uC);
            f32x2 hD = fp8pair(uD);
            accL += a0 * hA.x; accH += a1 * hA.y;
            accL += b0 * hB.x; accH += b1 * hB.y;
            accL += c0 * hC.x; accH += c1 * hC.y;
            accL += d0 * hD.x; accH += d1 * hD.y;
        }
    }

    float oL = accL / (den0 + 1e-16f) + bias[lane];
    float oH = accH / (den1 + 1e-16f) + bias[64 + lane];
    if (ACT) {
        oL = oL > 0.f ? oL : expm1f(oL);
        oH = oH > 0.f ? oH : expm1f(oH);
    }
    out[(size_t)node * 128 + lane] = f2bf(oL);
    out[(size_t)node * 128 + 64 + lane] = f2bf(oH);
}

// ---------------- GAT aggregation, 1 head (fp8 h, layer 2) -----------------
// Output bf16 (feeds pool only).

__global__ __launch_bounds__(256) void agg1_kernel(
    const int* __restrict__ row_ptr, const int* __restrict__ col,
    const unsigned char* __restrict__ h, const float* __restrict__ as1,
    const float* __restrict__ ad1, const float* __restrict__ bias,
    unsigned short* __restrict__ out, int n) {
    const int node = blockIdx.x * 4 + (threadIdx.x >> 6);
    const int lane = threadIdx.x & 63;
    if (node >= n) return;

    const int beg = row_ptr[node], end = row_ptr[node + 1];
    const float adv = ad1[node];
    const unsigned char* __restrict__ hb = h + lane;

    float ws = __expf(LRELU(as1[node] + adv));
    float acc = ws * fp8pair((unsigned)hb[(size_t)node << 6]).x;
    float den = ws;

    for (int base = beg; base < end; base += 64) {
        int cnt = end - base;
        if (cnt > 64) cnt = 64;
        int s = 0;
        float w = 0.f;
        if (lane < cnt) {
            s = col[base + lane];
            w = __expf(LRELU(as1[s] + adv));
        }
        float t = w;
        for (int off = 32; off; off >>= 1) t += __shfl_xor(t, off, 64);
        den += t;

        unsigned soff = (unsigned)s << 6;  // row byte offset (64 B)
        for (int j = 0; j < cnt; j += 4) {
            unsigned oA = readlane_u(soff, j);
            unsigned oB = readlane_u(soff, j + 1);
            unsigned oC = readlane_u(soff, j + 2);
            unsigned oD = readlane_u(soff, j + 3);
            float wA = readlane_f(w, j);
            float wB = readlane_f(w, j + 1);
            float wC = readlane_f(w, j + 2);
            float wD = readlane_f(w, j + 3);
            float hA = fp8pair((unsigned)hb[oA]).x;
            float hB = fp8pair((unsigned)hb[oB]).x;
            float hC = fp8pair((unsigned)hb[oC]).x;
            float hD = fp8pair((unsigned)hb[oD]).x;
            acc += wA * hA;
            acc += wB * hB;
            acc += wC * hC;
            acc += wD * hD;
        }
    }

    out[(size_t)node * 64 + lane] = f2bf(acc / (den + 1e-16f) + bias[lane]);
}

// ---------------- mean pool over sorted batch (bf16 in) --------------------

__global__ __launch_bounds__(256) void pool_kernel(
    const unsigned short* __restrict__ x, const int* __restrict__ batch,
    float* __restrict__ pooled, float* __restrict__ cnt, int n) {
    const int NPW = 16;
    int wid = blockIdx.x * (blockDim.x >> 6) + (threadIdx.x >> 6);
    int lane = threadIdx.x & 63;
    int start = wid * NPW;
    if (start >= n) return;
    int end = min(start + NPW, n);
    float acc = 0.f, c = 0.f;
    int cur = -1;
    for (int i = start; i < end; i++) {
        int b = batch[i];
        if (b != cur) {
            if (cur >= 0) {
                atomicAdd(&pooled[cur * 64 + lane], acc);
                if (lane == 0) atomicAdd(&cnt[cur], c);
            }
            cur = b;
            acc = 0.f;
            c = 0.f;
        }
        acc += bf2f(x[(size_t)i * 64 + lane]);
        c += 1.f;
    }
    if (cur >= 0) {
        atomicAdd(&pooled[cur * 64 + lane], acc);
        if (lane == 0) atomicAdd(&cnt[cur], c);
    }
}

// ---------------- MLP head: one block per graph row ------------------------

__global__ __launch_bounds__(256) void mlp_kernel(
    const float* __restrict__ pooled, const float* __restrict__ cnt,
    const float* __restrict__ obs,
    const float* __restrict__ Ws1, const float* __restrict__ bs1,
    const float* __restrict__ ln_g, const float* __restrict__ ln_b,
    const float* __restrict__ Ws2, const float* __restrict__ bs2,
    const float* __restrict__ Wa, const float* __restrict__ ba,
    const float* __restrict__ Wc, const float* __restrict__ bc,
    float* __restrict__ out_logits, float* __restrict__ out_value) {
    int b = blockIdx.x;
    int t = threadIdx.x;
    __shared__ float comb[192];
    __shared__ float red[256];
    __shared__ float hs[256];

    if (t < 64) {
        float c = cnt[b];
        c = c > 1.f ? c : 1.f;
        comb[t] = pooled[b * 64 + t] / c;
    } else if (t < 192) {
        comb[t] = obs[b * 128 + (t - 64)];
    }
    __syncthreads();

    float acc = bs1[t];
    for (int k = 0; k < 192; k++) acc += comb[k] * Ws1[k * 256 + t];

    red[t] = acc;
    __syncthreads();
    for (int off = 128; off; off >>= 1) {
        if (t < off) red[t] += red[t + off];
        __syncthreads();
    }
    float mu = red[0] / 256.f;
    __syncthreads();
    float d = acc - mu;
    red[t] = d * d;
    __syncthreads();
    for (int off = 128; off; off >>= 1) {
        if (t < off) red[t] += red[t + off];
        __syncthreads();
    }
    float var = red[0] / 256.f;
    float hn = d * rsqrtf(var + 1e-5f) * ln_g[t] + ln_b[t];
    hn = hn > 0.f ? hn : 0.f;
    __syncthreads();
    hs[t] = hn;
    __syncthreads();

    float acc2 = bs2[t];
    for (int k = 0; k < 256; k++) acc2 += hs[k] * Ws2[k * 256 + t];
    acc2 = acc2 > 0.f ? acc2 : 0.f;
    __syncthreads();
    hs[t] = acc2;
    __syncthreads();

    if (t < 16) {
        float a = ba[t];
        for (int k = 0; k < 256; k++) a += hs[k] * Wa[k * 16 + t];
        out_logits[b * 16 + t] = a;
    } else if (t == 16) {
        float v = bc[0];
        for (int k = 0; k < 256; k++) v += hs[k] * Wc[k];
        out_value[b] = v;
    }
}

// ---------------------------------------------------------------------------

extern "C" void kernel_launch(void* const* d_in, const int* in_sizes, int n_in,
                              void* d_out, int out_size, void* d_ws, size_t ws_size,
                              hipStream_t stream) {
    const float* obs    = (const float*)d_in[0];
    const float* nf     = (const float*)d_in[1];
    const int*   ei     = (const int*)d_in[2];
    const int*   batch  = (const int*)d_in[3];
    const float* W0     = (const float*)d_in[4];
    const float* a_src0 = (const float*)d_in[5];
    const float* a_dst0 = (const float*)d_in[6];
    const float* b0     = (const float*)d_in[7];
    const float* W1     = (const float*)d_in[8];
    const float* a_src1 = (const float*)d_in[9];
    const float* a_dst1 = (const float*)d_in[10];
    const float* b1     = (const float*)d_in[11];
    const float* W2     = (const float*)d_in[12];
    const float* a_src2 = (const float*)d_in[13];
    const float* a_dst2 = (const float*)d_in[14];
    const float* b2     = (const float*)d_in[15];
    const float* Ws1    = (const float*)d_in[16];
    const float* bs1    = (const float*)d_in[17];
    const float* ln_g   = (const float*)d_in[18];
    const float* ln_b   = (const float*)d_in[19];
    const float* Ws2    = (const float*)d_in[20];
    const float* bs2    = (const float*)d_in[21];
    const float* Wa     = (const float*)d_in[22];
    const float* ba     = (const float*)d_in[23];
    const float* Wc     = (const float*)d_in[24];
    const float* bc     = (const float*)d_in[25];

    const int N = in_sizes[3];
    const int E = in_sizes[2] / 2;
    const int B = in_sizes[0] / 128;
    const int* src = ei;
    const int* dstp = ei + E;

    // workspace carve (256B aligned)
    char* p = (char*)d_ws;
    auto alloc = [&](size_t bytes) -> void* {
        void* r = (void*)p;
        p += (bytes + 255) & ~(size_t)255;
        return r;
    };
    int nb = (N + 255) / 256;
    int*   row_ptr   = (int*)alloc((size_t)(N + 1) * 4);
    int*   col       = (int*)alloc((size_t)E * 4);
    int*   rank      = (int*)alloc((size_t)E * 4);
    unsigned char* hbuf = (unsigned char*)alloc((size_t)N * 128);       // fp8 interleaved
    unsigned short* xb = (unsigned short*)alloc((size_t)N * 128 * 2);   // bf16 features
    unsigned short* xbuf = (unsigned short*)alloc((size_t)N * 64 * 2);  // final layer bf16
    float* as_       = (float*)alloc((size_t)N * 2 * 4);
    float* ad_       = (float*)alloc((size_t)N * 2 * 4);
    unsigned short* Wf1 = (unsigned short*)alloc((size_t)8 * 4 * 64 * 8 * 2);
    unsigned short* Wf2 = (unsigned short*)alloc((size_t)4 * 4 * 64 * 8 * 2);
    float* pooled    = (float*)alloc((size_t)(B * 64 + B) * 4);
    float* cnt       = pooled + (size_t)B * 64;
    // scratch (cursor + blockSums) aliases xb region: CSR build completes
    // (stream-ordered) before xb's first write (agg2, layer 0).
    int* cursor    = (int*)xb;
    int* blockSums = cursor + N;         // nb + 1

    float* out_logits = (float*)d_out;
    float* out_value  = out_logits + (size_t)B * 16;

    // ---- CSR build: sharded count(+rank) -> 3-kernel scan -> atomic-free scatter
    hipMemsetAsync(cursor, 0, (size_t)N * 4, stream);
    int csr_V = (E + 8 * 256 - 1) / (8 * 256);
    int csr_T = csr_V * 256;
    int csr_blocks = csr_V * 8;
    count_kernel<<<csr_blocks, 256, 0, stream>>>(dstp, cursor, rank, E, csr_T, N);
    scan_block_kernel<<<nb, 256, 0, stream>>>(cursor, row_ptr, blockSums, N);
    scan_sums_kernel<<<1, 256, 0, stream>>>(blockSums, nb);
    scan_finalize_kernel<<<(N + 1 + 255) / 256, 256, 0, stream>>>(row_ptr, blockSums, N, nb);
    scatter_kernel<<<csr_blocks, 256, 0, stream>>>(src, dstp, row_ptr, rank, col, E, csr_T, N);

    // ---- fused W pack + pooled/cnt zero ----
    {
        int total = 8 * 4 * 64 + 4 * 4 * 64 + (B * 64 + B);
        pack_all_kernel<<<(total + 255) / 256, 256, 0, stream>>>(
            W1, W2, Wf1, Wf2, pooled, B * 64 + B);
    }

    // ---- GAT layer 0: in=8 -> h=[N,2,64] concat, elu ----
    transform_kernel<8, 128, 2><<<(N + 7) / 8, 128, 0, stream>>>(
        nf, W0, a_src0, a_dst0, hbuf, as_, ad_, N);
    agg2_kernel<1><<<(N + 3) / 4, 256, 0, stream>>>(
        row_ptr, col, hbuf, (const float2*)as_, (const float2*)ad_, b0, xb, N);

    // ---- GAT layer 1: in=128 -> concat, elu (MFMA transform) ----
    transform_mfma_kernel<128, 2><<<(N + 63) / 64, 256, 0, stream>>>(
        xb, Wf1, a_src1, a_dst1, hbuf, as_, ad_, N);
    agg2_kernel<1><<<(N + 3) / 4, 256, 0, stream>>>(
        row_ptr, col, hbuf, (const float2*)as_, (const float2*)ad_, b1, xb, N);

    // ---- GAT layer 2: in=128 -> heads=1, out=64 (MFMA transform) ----
    transform_mfma_kernel<64, 1><<<(N + 63) / 64, 256, 0, stream>>>(
        xb, Wf2, a_src2, a_dst2, hbuf, as_, ad_, N);
    agg1_kernel<<<(N + 3) / 4, 256, 0, stream>>>(
        row_ptr, col, hbuf, as_, ad_, b2, xbuf, N);

    // ---- mean pool + MLP head ----
    {
        int waves = (N + 15) / 16;
        int blocks = (waves + 3) / 4;
        pool_kernel<<<blocks, 256, 0, stream>>>(xbuf, batch, pooled, cnt, N);
    }
    mlp_kernel<<<B, 256, 0, stream>>>(pooled, cnt, obs, Ws1, bs1, ln_g, ln_b,
                                      Ws2, bs2, Wa, ba, Wc, bc,
                                      out_logits, out_value);
}

// Round 16
// 354.790 us; speedup vs baseline: 2.5254x; 1.0088x over previous
//
#include <hip/hip_runtime.h>
#include <math.h>

// ---------------------------------------------------------------------------
// GATPolicy: 3x GATConv (with self loops) + mean-pool + MLP head.
// CSR-by-dst via dst-range sharded count/scatter (XCD-local lines); 2-kernel
// scan (block scan -> finalize, which redundantly scans the <=256 blockSums
// per block instead of a separate 1-block kernel). Scatter is ATOMIC-FREE:
// count's atomicAdd return value is the edge's rank within its row, stored to
// rank[e]; scatter does col[row_ptr[dst]+rank] = src. (r13 lesson: never
// chain blocks across XCDs — cross-XCD handshakes cost ~2.7us per link.)
// h stored FP8 e4m3 head-interleaved (byte pair at node*128+2*ch); agg inner
// loop branch-free: 3 readlane + add + ushort load + cvt_pk_f32_fp8 + 2 fma.
// Inter-layer features bf16; K=128 transforms via mfma_f32_16x16x32_bf16.
// prep_kernel fuses cursor-zero + W pack + pooled-zero (1 dispatch).
// ---------------------------------------------------------------------------

#define LRELU(x) ((x) > 0.f ? (x) : 0.2f * (x))

typedef short bf16x8 __attribute__((ext_vector_type(8)));
typedef float f32x4 __attribute__((ext_vector_type(4)));
typedef float f32x2 __attribute__((ext_vector_type(2)));

__device__ __forceinline__ float readlane_f(float v, int lane) {
    return __int_as_float(__builtin_amdgcn_readlane(__float_as_int(v), lane));
}
__device__ __forceinline__ unsigned readlane_u(unsigned v, int lane) {
    return (unsigned)__builtin_amdgcn_readlane((int)v, lane);
}
__device__ __forceinline__ unsigned short f2bf(float f) {
    unsigned int u = __float_as_uint(f);
    u = (u + 0x7fffu + ((u >> 16) & 1u)) >> 16;  // RNE
    return (unsigned short)u;
}
__device__ __forceinline__ float bf2f(unsigned short u) {
    return __uint_as_float((unsigned int)u << 16);
}
__device__ __forceinline__ unsigned char f2fp8(float f) {
    return (unsigned char)(__builtin_amdgcn_cvt_pk_fp8_f32(f, f, 0, false) & 0xff);
}
__device__ __forceinline__ f32x2 fp8pair(unsigned int u) {
    return __builtin_amdgcn_cvt_pk_f32_fp8(u, false);  // bytes 0,1
}

// ---------------- prep: cursor zero + W pack + pooled zero -----------------

__global__ __launch_bounds__(256) void prep_kernel(
    int* __restrict__ cursor, int n,
    const float* __restrict__ W1, const float* __restrict__ W2,
    unsigned short* __restrict__ Wf1, unsigned short* __restrict__ Wf2,
    float* __restrict__ pooled, int poolN) {
    const int n1 = 8 * 4 * 64;   // W1 fragment rows (OUT=128)
    const int n2 = 4 * 4 * 64;   // W2 fragment rows (OUT=64)
    int gid = blockIdx.x * 256 + threadIdx.x;
    if (gid < n) {
        cursor[gid] = 0;
    } else if (gid < n + n1) {
        int idx = gid - n;
        int lane = idx & 63, ts = idx >> 6;
        int s = ts & 3, t = ts >> 2;
        int quad = lane >> 4, cn = lane & 15;
#pragma unroll
        for (int j = 0; j < 8; j++)
            Wf1[idx * 8 + j] = f2bf(W1[(s * 32 + quad * 8 + j) * 128 + t * 16 + cn]);
    } else if (gid < n + n1 + n2) {
        int idx = gid - n - n1;
        int lane = idx & 63, ts = idx >> 6;
        int s = ts & 3, t = ts >> 2;
        int quad = lane >> 4, cn = lane & 15;
#pragma unroll
        for (int j = 0; j < 8; j++)
            Wf2[idx * 8 + j] = f2bf(W2[(s * 32 + quad * 8 + j) * 64 + t * 16 + cn]);
    } else {
        int k = gid - n - n1 - n2;
        if (k < poolN) pooled[k] = 0.f;
    }
}

// ---------------- CSR build (dst-range sharded, ILP-batched) ----------------
// count: atomicAdd returns the edge's rank within its row (one shard per row);
// stored to rank[] so scatter needs no atomics.

__global__ __launch_bounds__(256) void count_kernel(
    const int* __restrict__ dst, int* __restrict__ cursor,
    int* __restrict__ rank, int e, int T, int n) {
    int x = blockIdx.x & 7;
    int lo = (int)(((long long)x * n) >> 3);
    int hi = (int)(((long long)(x + 1) * n) >> 3);
    int i0 = (blockIdx.x >> 3) * 256 + threadIdx.x;
    int ij[8], d[8];
#pragma unroll
    for (int j = 0; j < 8; j++) {
        ij[j] = i0 + j * T;
        int dd = (ij[j] < e) ? dst[ij[j]] : -1;
        d[j] = (dd >= lo && dd < hi) ? dd : -1;
    }
    int r[8];
#pragma unroll
    for (int j = 0; j < 8; j++) {
        r[j] = (d[j] >= 0) ? atomicAdd(&cursor[d[j]], 1) : 0;
    }
#pragma unroll
    for (int j = 0; j < 8; j++) {
        if (d[j] >= 0) rank[ij[j]] = r[j];
    }
}

__global__ __launch_bounds__(256) void scan_block_kernel(
    const int* __restrict__ in, int* __restrict__ out_local,
    int* __restrict__ blockSums, int n) {
    __shared__ int lds[256];
    int i = blockIdx.x * 256 + threadIdx.x;
    int v = (i < n) ? in[i] : 0;
    lds[threadIdx.x] = v;
    __syncthreads();
    for (int off = 1; off < 256; off <<= 1) {
        int t = (threadIdx.x >= off) ? lds[threadIdx.x - off] : 0;
        __syncthreads();
        lds[threadIdx.x] += t;
        __syncthreads();
    }
    if (i < n) out_local[i] = lds[threadIdx.x] - v;  // block-local exclusive
    if (threadIdx.x == 255) blockSums[blockIdx.x] = lds[255];
}

// Finalize: every block redundantly scans blockSums (nb <= 256) in LDS and
// applies exclusive[bid] (bid == i>>8 for all its elements). No cross-block
// communication; one dispatch replaces scan_sums + finalize.
__global__ __launch_bounds__(256) void scan_finalize_kernel(
    int* __restrict__ row_ptr, const int* __restrict__ blockSums, int n, int nb) {
    __shared__ int lds[256];
    int t = threadIdx.x;
    int v = (t < nb) ? blockSums[t] : 0;
    lds[t] = v;
    __syncthreads();
    for (int off = 1; off < 256; off <<= 1) {
        int u = (t >= off) ? lds[t - off] : 0;
        __syncthreads();
        lds[t] += u;
        __syncthreads();
    }
    const int bid = blockIdx.x;
    const int base = (bid > 0) ? lds[bid - 1] : 0;  // exclusive prefix, bid<256
    const int total = lds[nb - 1];
    int i = bid * 256 + t;
    if (i < n) {
        row_ptr[i] += base;
    } else if (i == n) {
        row_ptr[n] = total;
    }
}

// Atomic-free: col[row_ptr[dst] + rank] = src. Sharded so col writes for a
// row come from one XCD (shard = pure function of dst value).
__global__ __launch_bounds__(256) void scatter_kernel(
    const int* __restrict__ src, const int* __restrict__ dst,
    const int* __restrict__ row_ptr, const int* __restrict__ rank,
    int* __restrict__ col, int e, int T, int n) {
    int x = blockIdx.x & 7;
    int lo = (int)(((long long)x * n) >> 3);
    int hi = (int)(((long long)(x + 1) * n) >> 3);
    int i0 = (blockIdx.x >> 3) * 256 + threadIdx.x;
    int s[8], d[8], r[8];
#pragma unroll
    for (int j = 0; j < 8; j++) {
        int ij = i0 + j * T;
        bool v = ij < e;
        int dd = v ? dst[ij] : -1;
        d[j] = (dd >= lo && dd < hi) ? dd : -1;
        s[j] = v ? src[ij] : 0;
        r[j] = v ? rank[ij] : 0;
    }
    int p[8];
#pragma unroll
    for (int j = 0; j < 8; j++) {
        p[j] = (d[j] >= 0) ? row_ptr[d[j]] + r[j] : 0;
    }
#pragma unroll
    for (int j = 0; j < 8; j++) {
        if (d[j] >= 0) col[p[j]] = s[j];
    }
}

// fp8 h byte position for channel c: 2-head interleaved pairs, 1-head flat
template <int OUT, int HEADS>
__device__ __forceinline__ int hpos8(int c) {
    return (HEADS == 2) ? (2 * (c & 63) + (c >> 6)) : c;
}

// ---------------- layer-0 transform (K=8, VALU): h(fp8)=x@W, as/ad ---------

template <int K, int OUT, int HEADS>
__global__ __launch_bounds__(OUT) void transform_kernel(
    const float* __restrict__ x, const float* __restrict__ W,
    const float* __restrict__ a_src, const float* __restrict__ a_dst,
    unsigned char* __restrict__ h, float* __restrict__ as_o, float* __restrict__ ad_o,
    int n) {
    constexpr int NPB = 8;
    __shared__ float xs[NPB][K];
    const int tid = threadIdx.x;
    const int node0 = blockIdx.x * NPB;

    for (int idx = tid; idx < NPB * K; idx += OUT) {
        int ni = idx / K, k = idx - ni * K;
        int ng = node0 + ni;
        xs[ni][k] = (ng < n) ? x[(size_t)ng * K + k] : 0.f;
    }
    __syncthreads();

    float acc[NPB];
#pragma unroll
    for (int i = 0; i < NPB; i++) acc[i] = 0.f;
    for (int k = 0; k < K; k++) {
        float wk = W[k * OUT + tid];
#pragma unroll
        for (int i = 0; i < NPB; i++) acc[i] += xs[i][k] * wk;
    }

    const int lane = tid & 63;
    const int head = (HEADS == 2) ? (tid >> 6) : 0;
    const int pos = hpos8<OUT, HEADS>(tid);
    const float av = a_src[tid];
    const float dv = a_dst[tid];
#pragma unroll
    for (int i = 0; i < NPB; i++) {
        int ng = node0 + i;
        if (ng >= n) break;
        h[(size_t)ng * OUT + pos] = f2fp8(acc[i]);
        float ps = acc[i] * av, pd = acc[i] * dv;
        for (int off = 32; off; off >>= 1) {
            ps += __shfl_xor(ps, off, 64);
            pd += __shfl_xor(pd, off, 64);
        }
        if (lane == 0) {
            as_o[ng * HEADS + head] = ps;
            ad_o[ng * HEADS + head] = pd;
        }
    }
}

// ---------------- MFMA transform (K=128): h(fp8)=xb(bf16)@W, as/ad ---------

template <int OUT, int HEADS>
__global__ __launch_bounds__(256) void transform_mfma_kernel(
    const unsigned short* __restrict__ xb, const unsigned short* __restrict__ Wf,
    const float* __restrict__ a_src, const float* __restrict__ a_dst,
    unsigned char* __restrict__ h, float* __restrict__ as_o, float* __restrict__ ad_o,
    int n) {
    constexpr int T = OUT / 16, S = 4;  // K = 128
    const int w = threadIdx.x >> 6, lane = threadIdx.x & 63;
    const int node0 = (blockIdx.x * 4 + w) * 16;
    if (node0 >= n) return;
    const int quad = lane >> 4, col = lane & 15;

    const int arow = node0 + col;
    const bool aok = arow < n;
    bf16x8 a[S];
    const unsigned short* xrow = xb + (size_t)arow * 128 + quad * 8;
#pragma unroll
    for (int s = 0; s < S; s++) {
        bf16x8 z = {0, 0, 0, 0, 0, 0, 0, 0};
        a[s] = aok ? *(const bf16x8*)(xrow + s * 32) : z;
    }

    f32x4 acc[T];
#pragma unroll
    for (int t = 0; t < T; t++) acc[t] = (f32x4){0.f, 0.f, 0.f, 0.f};

#pragma unroll
    for (int s = 0; s < S; s++) {
#pragma unroll
        for (int t = 0; t < T; t++) {
            bf16x8 b = *(const bf16x8*)(Wf + ((size_t)(t * S + s) * 64 + lane) * 8);
            acc[t] = __builtin_amdgcn_mfma_f32_16x16x32_bf16(a[s], b, acc[t], 0, 0, 0);
        }
    }

#pragma unroll
    for (int t = 0; t < T; t++) {
        int pos = hpos8<OUT, HEADS>(t * 16 + col);
#pragma unroll
        for (int r = 0; r < 4; r++) {
            int m = node0 + quad * 4 + r;
            if (m < n) h[(size_t)m * OUT + pos] = f2fp8(acc[t][r]);
        }
    }

#pragma unroll
    for (int r = 0; r < 4; r++) {
        float s0 = 0.f, s1 = 0.f, d0 = 0.f, d1 = 0.f;
#pragma unroll
        for (int t = 0; t < T; t++) {
            float av = a_src[t * 16 + col];
            float dv = a_dst[t * 16 + col];
            float v = acc[t][r];
            if (HEADS == 2 && t >= T / 2) { s1 += v * av; d1 += v * dv; }
            else                          { s0 += v * av; d0 += v * dv; }
        }
        for (int off = 8; off; off >>= 1) {
            s0 += __shfl_xor(s0, off, 64);
            d0 += __shfl_xor(d0, off, 64);
            if (HEADS == 2) {
                s1 += __shfl_xor(s1, off, 64);
                d1 += __shfl_xor(d1, off, 64);
            }
        }
        int m = node0 + quad * 4 + r;
        if (m < n) {
            if (HEADS == 2) {
                if (col == 0)      { as_o[m * 2] = s0;     ad_o[m * 2] = d0; }
                else if (col == 1) { as_o[m * 2 + 1] = s1; ad_o[m * 2 + 1] = d1; }
            } else {
                if (col == 0) { as_o[m] = s0; ad_o[m] = d0; }
            }
        }
    }
}

// ---------------- GAT aggregation, 2 heads (fp8 h): one wave per node ------

template <int ACT>  // 1 = elu
__global__ __launch_bounds__(256) void agg2_kernel(
    const int* __restrict__ row_ptr, const int* __restrict__ col,
    const unsigned char* __restrict__ h, const float2* __restrict__ as2,
    const float2* __restrict__ ad2, const float* __restrict__ bias,
    unsigned short* __restrict__ out, int n) {
    const int node = blockIdx.x * 4 + (threadIdx.x >> 6);
    const int lane = threadIdx.x & 63;
    if (node >= n) return;

    const int beg = row_ptr[node], end = row_ptr[node + 1];
    const float2 adv = ad2[node];
    const unsigned char* __restrict__ hb = h + 2 * lane;

    // self-loop
    const float2 avs = as2[node];
    float w0s = __expf(LRELU(avs.x + adv.x));
    float w1s = __expf(LRELU(avs.y + adv.y));
    unsigned int us = *(const unsigned short*)(hb + ((size_t)node << 7));
    f32x2 hvs = fp8pair(us);
    float accL = w0s * hvs.x, accH = w1s * hvs.y;
    float den0 = w0s, den1 = w1s;

    for (int base = beg; base < end; base += 64) {
        int cnt = end - base;
        if (cnt > 64) cnt = 64;
        int s = 0;
        float w0 = 0.f, w1 = 0.f;
        if (lane < cnt) {
            s = col[base + lane];
            float2 av = as2[s];
            w0 = __expf(LRELU(av.x + adv.x));
            w1 = __expf(LRELU(av.y + adv.y));
        }
        float t0 = w0, t1 = w1;
        for (int off = 32; off; off >>= 1) {
            t0 += __shfl_xor(t0, off, 64);
            t1 += __shfl_xor(t1, off, 64);
        }
        den0 += t0;
        den1 += t1;

        unsigned soff = (unsigned)s << 7;  // row byte offset (128 B)
        for (int j = 0; j < cnt; j += 4) {  // j <= 60; pads carry w=0
            unsigned oA = readlane_u(soff, j);
            unsigned oB = readlane_u(soff, j + 1);
            unsigned oC = readlane_u(soff, j + 2);
            unsigned oD = readlane_u(soff, j + 3);
            float a0 = readlane_f(w0, j),     a1 = readlane_f(w1, j);
            float b0 = readlane_f(w0, j + 1), b1 = readlane_f(w1, j + 1);
            float c0 = readlane_f(w0, j + 2), c1 = readlane_f(w1, j + 2);
            float d0 = readlane_f(w0, j + 3), d1 = readlane_f(w1, j + 3);
            unsigned uA = *(const unsigned short*)(hb + oA);
            unsigned uB = *(const unsigned short*)(hb + oB);
            unsigned uC = *(const unsigned short*)(hb + oC);
            unsigned uD = *(const unsigned short*)(hb + oD);
            f32x2 hA = fp8pair(uA);
            f32x2 hB = fp8pair(uB);
            f32x2 hC = fp8pair(uC);
            f32x2 hD = fp8pair(uD);
            accL += a0 * hA.x; accH += a1 * hA.y;
            accL += b0 * hB.x; accH += b1 * hB.y;
            accL += c0 * hC.x; accH += c1 * hC.y;
            accL += d0 * hD.x; accH += d1 * hD.y;
        }
    }

    float oL = accL / (den0 + 1e-16f) + bias[lane];
    float oH = accH / (den1 + 1e-16f) + bias[64 + lane];
    if (ACT) {
        oL = oL > 0.f ? oL : expm1f(oL);
        oH = oH > 0.f ? oH : expm1f(oH);
    }
    out[(size_t)node * 128 + lane] = f2bf(oL);
    out[(size_t)node * 128 + 64 + lane] = f2bf(oH);
}

// ---------------- GAT aggregation, 1 head (fp8 h, layer 2) -----------------
// Output bf16 (feeds pool only).

__global__ __launch_bounds__(256) void agg1_kernel(
    const int* __restrict__ row_ptr, const int* __restrict__ col,
    const unsigned char* __restrict__ h, const float* __restrict__ as1,
    const float* __restrict__ ad1, const float* __restrict__ bias,
    unsigned short* __restrict__ out, int n) {
    const int node = blockIdx.x * 4 + (threadIdx.x >> 6);
    const int lane = threadIdx.x & 63;
    if (node >= n) return;

    const int beg = row_ptr[node], end = row_ptr[node + 1];
    const float adv = ad1[node];
    const unsigned char* __restrict__ hb = h + lane;

    float ws = __expf(LRELU(as1[node] + adv));
    float acc = ws * fp8pair((unsigned)hb[(size_t)node << 6]).x;
    float den = ws;

    for (int base = beg; base < end; base += 64) {
        int cnt = end - base;
        if (cnt > 64) cnt = 64;
        int s = 0;
        float w = 0.f;
        if (lane < cnt) {
            s = col[base + lane];
            w = __expf(LRELU(as1[s] + adv));
        }
        float t = w;
        for (int off = 32; off; off >>= 1) t += __shfl_xor(t, off, 64);
        den += t;

        unsigned soff = (unsigned)s << 6;  // row byte offset (64 B)
        for (int j = 0; j < cnt; j += 4) {
            unsigned oA = readlane_u(soff, j);
            unsigned oB = readlane_u(soff, j + 1);
            unsigned oC = readlane_u(soff, j + 2);
            unsigned oD = readlane_u(soff, j + 3);
            float wA = readlane_f(w, j);
            float wB = readlane_f(w, j + 1);
            float wC = readlane_f(w, j + 2);
            float wD = readlane_f(w, j + 3);
            float hA = fp8pair((unsigned)hb[oA]).x;
            float hB = fp8pair((unsigned)hb[oB]).x;
            float hC = fp8pair((unsigned)hb[oC]).x;
            float hD = fp8pair((unsigned)hb[oD]).x;
            acc += wA * hA;
            acc += wB * hB;
            acc += wC * hC;
            acc += wD * hD;
        }
    }

    out[(size_t)node * 64 + lane] = f2bf(acc / (den + 1e-16f) + bias[lane]);
}

// ---------------- mean pool over sorted batch (bf16 in) --------------------

__global__ __launch_bounds__(256) void pool_kernel(
    const unsigned short* __restrict__ x, const int* __restrict__ batch,
    float* __restrict__ pooled, float* __restrict__ cnt, int n) {
    const int NPW = 16;
    int wid = blockIdx.x * (blockDim.x >> 6) + (threadIdx.x >> 6);
    int lane = threadIdx.x & 63;
    int start = wid * NPW;
    if (start >= n) return;
    int end = min(start + NPW, n);
    float acc = 0.f, c = 0.f;
    int cur = -1;
    for (int i = start; i < end; i++) {
        int b = batch[i];
        if (b != cur) {
            if (cur >= 0) {
                atomicAdd(&pooled[cur * 64 + lane], acc);
                if (lane == 0) atomicAdd(&cnt[cur], c);
            }
            cur = b;
            acc = 0.f;
            c = 0.f;
        }
        acc += bf2f(x[(size_t)i * 64 + lane]);
        c += 1.f;
    }
    if (cur >= 0) {
        atomicAdd(&pooled[cur * 64 + lane], acc);
        if (lane == 0) atomicAdd(&cnt[cur], c);
    }
}

// ---------------- MLP head: one block per graph row ------------------------

__global__ __launch_bounds__(256) void mlp_kernel(
    const float* __restrict__ pooled, const float* __restrict__ cnt,
    const float* __restrict__ obs,
    const float* __restrict__ Ws1, const float* __restrict__ bs1,
    const float* __restrict__ ln_g, const float* __restrict__ ln_b,
    const float* __restrict__ Ws2, const float* __restrict__ bs2,
    const float* __restrict__ Wa, const float* __restrict__ ba,
    const float* __restrict__ Wc, const float* __restrict__ bc,
    float* __restrict__ out_logits, float* __restrict__ out_value) {
    int b = blockIdx.x;
    int t = threadIdx.x;
    __shared__ float comb[192];
    __shared__ float red[256];
    __shared__ float hs[256];

    if (t < 64) {
        float c = cnt[b];
        c = c > 1.f ? c : 1.f;
        comb[t] = pooled[b * 64 + t] / c;
    } else if (t < 192) {
        comb[t] = obs[b * 128 + (t - 64)];
    }
    __syncthreads();

    float acc = bs1[t];
    for (int k = 0; k < 192; k++) acc += comb[k] * Ws1[k * 256 + t];

    red[t] = acc;
    __syncthreads();
    for (int off = 128; off; off >>= 1) {
        if (t < off) red[t] += red[t + off];
        __syncthreads();
    }
    float mu = red[0] / 256.f;
    __syncthreads();
    float d = acc - mu;
    red[t] = d * d;
    __syncthreads();
    for (int off = 128; off; off >>= 1) {
        if (t < off) red[t] += red[t + off];
        __syncthreads();
    }
    float var = red[0] / 256.f;
    float hn = d * rsqrtf(var + 1e-5f) * ln_g[t] + ln_b[t];
    hn = hn > 0.f ? hn : 0.f;
    __syncthreads();
    hs[t] = hn;
    __syncthreads();

    float acc2 = bs2[t];
    for (int k = 0; k < 256; k++) acc2 += hs[k] * Ws2[k * 256 + t];
    acc2 = acc2 > 0.f ? acc2 : 0.f;
    __syncthreads();
    hs[t] = acc2;
    __syncthreads();

    if (t < 16) {
        float a = ba[t];
        for (int k = 0; k < 256; k++) a += hs[k] * Wa[k * 16 + t];
        out_logits[b * 16 + t] = a;
    } else if (t == 16) {
        float v = bc[0];
        for (int k = 0; k < 256; k++) v += hs[k] * Wc[k];
        out_value[b] = v;
    }
}

// ---------------------------------------------------------------------------

extern "C" void kernel_launch(void* const* d_in, const int* in_sizes, int n_in,
                              void* d_out, int out_size, void* d_ws, size_t ws_size,
                              hipStream_t stream) {
    const float* obs    = (const float*)d_in[0];
    const float* nf     = (const float*)d_in[1];
    const int*   ei     = (const int*)d_in[2];
    const int*   batch  = (const int*)d_in[3];
    const float* W0     = (const float*)d_in[4];
    const float* a_src0 = (const float*)d_in[5];
    const float* a_dst0 = (const float*)d_in[6];
    const float* b0     = (const float*)d_in[7];
    const float* W1     = (const float*)d_in[8];
    const float* a_src1 = (const float*)d_in[9];
    const float* a_dst1 = (const float*)d_in[10];
    const float* b1     = (const float*)d_in[11];
    const float* W2     = (const float*)d_in[12];
    const float* a_src2 = (const float*)d_in[13];
    const float* a_dst2 = (const float*)d_in[14];
    const float* b2     = (const float*)d_in[15];
    const float* Ws1    = (const float*)d_in[16];
    const float* bs1    = (const float*)d_in[17];
    const float* ln_g   = (const float*)d_in[18];
    const float* ln_b   = (const float*)d_in[19];
    const float* Ws2    = (const float*)d_in[20];
    const float* bs2    = (const float*)d_in[21];
    const float* Wa     = (const float*)d_in[22];
    const float* ba     = (const float*)d_in[23];
    const float* Wc     = (const float*)d_in[24];
    const float* bc     = (const float*)d_in[25];

    const int N = in_sizes[3];
    const int E = in_sizes[2] / 2;
    const int B = in_sizes[0] / 128;
    const int* src = ei;
    const int* dstp = ei + E;

    // workspace carve (256B aligned)
    char* p = (char*)d_ws;
    auto alloc = [&](size_t bytes) -> void* {
        void* r = (void*)p;
        p += (bytes + 255) & ~(size_t)255;
        return r;
    };
    int nb = (N + 255) / 256;
    int*   row_ptr   = (int*)alloc((size_t)(N + 1) * 4);
    int*   col       = (int*)alloc((size_t)E * 4);
    int*   rank      = (int*)alloc((size_t)E * 4);
    unsigned char* hbuf = (unsigned char*)alloc((size_t)N * 128);       // fp8 interleaved
    unsigned short* xb = (unsigned short*)alloc((size_t)N * 128 * 2);   // bf16 features
    unsigned short* xbuf = (unsigned short*)alloc((size_t)N * 64 * 2);  // final layer bf16
    float* as_       = (float*)alloc((size_t)N * 2 * 4);
    float* ad_       = (float*)alloc((size_t)N * 2 * 4);
    unsigned short* Wf1 = (unsigned short*)alloc((size_t)8 * 4 * 64 * 8 * 2);
    unsigned short* Wf2 = (unsigned short*)alloc((size_t)4 * 4 * 64 * 8 * 2);
    float* pooled    = (float*)alloc((size_t)(B * 64 + B) * 4);
    float* cnt       = pooled + (size_t)B * 64;
    // scratch (cursor + blockSums) aliases xb region: CSR build completes
    // (stream-ordered) before xb's first write (agg2, layer 0).
    int* cursor    = (int*)xb;
    int* blockSums = cursor + N;         // nb + 1

    float* out_logits = (float*)d_out;
    float* out_value  = out_logits + (size_t)B * 16;

    // ---- prep: cursor zero + W pack + pooled zero (1 dispatch) ----
    {
        int total = N + 8 * 4 * 64 + 4 * 4 * 64 + (B * 64 + B);
        prep_kernel<<<(total + 255) / 256, 256, 0, stream>>>(
            cursor, N, W1, W2, Wf1, Wf2, pooled, B * 64 + B);
    }

    // ---- CSR build: sharded count(+rank) -> 2-kernel scan -> atomic-free scatter
    int csr_V = (E + 8 * 256 - 1) / (8 * 256);
    int csr_T = csr_V * 256;
    int csr_blocks = csr_V * 8;
    count_kernel<<<csr_blocks, 256, 0, stream>>>(dstp, cursor, rank, E, csr_T, N);
    scan_block_kernel<<<nb, 256, 0, stream>>>(cursor, row_ptr, blockSums, N);
    scan_finalize_kernel<<<(N + 1 + 255) / 256, 256, 0, stream>>>(row_ptr, blockSums, N, nb);
    scatter_kernel<<<csr_blocks, 256, 0, stream>>>(src, dstp, row_ptr, rank, col, E, csr_T, N);

    // ---- GAT layer 0: in=8 -> h=[N,2,64] concat, elu ----
    transform_kernel<8, 128, 2><<<(N + 7) / 8, 128, 0, stream>>>(
        nf, W0, a_src0, a_dst0, hbuf, as_, ad_, N);
    agg2_kernel<1><<<(N + 3) / 4, 256, 0, stream>>>(
        row_ptr, col, hbuf, (const float2*)as_, (const float2*)ad_, b0, xb, N);

    // ---- GAT layer 1: in=128 -> concat, elu (MFMA transform) ----
    transform_mfma_kernel<128, 2><<<(N + 63) / 64, 256, 0, stream>>>(
        xb, Wf1, a_src1, a_dst1, hbuf, as_, ad_, N);
    agg2_kernel<1><<<(N + 3) / 4, 256, 0, stream>>>(
        row_ptr, col, hbuf, (const float2*)as_, (const float2*)ad_, b1, xb, N);

    // ---- GAT layer 2: in=128 -> heads=1, out=64 (MFMA transform) ----
    transform_mfma_kernel<64, 1><<<(N + 63) / 64, 256, 0, stream>>>(
        xb, Wf2, a_src2, a_dst2, hbuf, as_, ad_, N);
    agg1_kernel<<<(N + 3) / 4, 256, 0, stream>>>(
        row_ptr, col, hbuf, as_, ad_, b2, xbuf, N);

    // ---- mean pool + MLP head ----
    {
        int waves = (N + 15) / 16;
        int blocks = (waves + 3) / 4;
        pool_kernel<<<blocks, 256, 0, stream>>>(xbuf, batch, pooled, cnt, N);
    }
    mlp_kernel<<<B, 256, 0, stream>>>(pooled, cnt, obs, Ws1, bs1, ln_g, ln_b,
                                      Ws2, bs2, Wa, ba, Wc, bc,
                                      out_logits, out_value);
}